// Round 1
// baseline (1044.941 us; speedup 1.0000x reference)
//
#include <hip/hip_runtime.h>
#include <hip/hip_bf16.h>

#define NN 100000   // nodes
#define NE 600000   // edges (before self-loops; self-loops handled analytically)

// ---------------- degree / normalization ----------------
__global__ __launch_bounds__(256) void k_deg_init(float* __restrict__ deg) {
    int i = blockIdx.x * 256 + threadIdx.x;
    if (i < NN) deg[i] = 1.0f;   // self-loop contributes 1
}
__global__ __launch_bounds__(256) void k_deg_count(const int* __restrict__ dst,
                                                   float* __restrict__ deg) {
    int e = blockIdx.x * 256 + threadIdx.x;
    if (e < NE) atomicAdd(&deg[dst[e]], 1.0f);
}
__global__ __launch_bounds__(256) void k_dis(float* __restrict__ deg) {
    int i = blockIdx.x * 256 + threadIdx.x;
    if (i < NN) deg[i] = rsqrtf(deg[i]);   // deg >= 1 always (self-loop)
}
__global__ __launch_bounds__(256) void k_norm(const int* __restrict__ src,
                                              const int* __restrict__ dst,
                                              const float* __restrict__ dis,
                                              float* __restrict__ nrm) {
    int e = blockIdx.x * 256 + threadIdx.x;
    if (e < NE) nrm[e] = dis[src[e]] * dis[dst[e]];
}

// ---------------- GEMM: Y[N,128] = X[N,128] @ W[128,128] ----------------
// Block = 256 threads, tile = 32 rows x 128 cols, 4x4 outputs/thread.
// K split into two 64-halves staged in LDS. X staged transposed with pad 36
// so compute reads are aligned ds_read_b128.
__global__ __launch_bounds__(256) void k_gemm128(const float* __restrict__ X,
                                                 const float* __restrict__ W,
                                                 float* __restrict__ Y) {
    __shared__ float WL[64 * 128];   // 32 KB: [k][col]
    __shared__ float XT[64 * 36];    // 9 KB:  [k][row(32) + pad]
    const int t = threadIdx.x;
    const int rbase = blockIdx.x * 32;        // 100000 % 32 == 0, no guard
    const int cg = t & 31;                    // cols 4*cg..4*cg+3
    const int rg = t >> 5;                    // rows 4*rg..4*rg+3
    float acc[4][4] = {};

    for (int k0 = 0; k0 < 128; k0 += 64) {
        // stage W rows k0..k0+63 (contiguous 8192 floats), coalesced float4
        {
            const float4* Wg = (const float4*)(W + k0 * 128);
            float4* Ws = (float4*)WL;
            #pragma unroll
            for (int i = 0; i < 8; ++i) Ws[t + 256 * i] = Wg[t + 256 * i];
        }
        // stage X transposed: XT[k][r] = X[rbase+r][k0+k]
        {
            int r = t >> 6;        // 0..3
            int k = t & 63;        // coalesced read along k
            #pragma unroll
            for (int i = 0; i < 8; ++i)
                XT[k * 36 + (r + 4 * i)] = X[(rbase + r + 4 * i) * 128 + k0 + k];
        }
        __syncthreads();
        #pragma unroll 8
        for (int k = 0; k < 64; ++k) {
            const float4 xv = *(const float4*)(XT + k * 36 + 4 * rg);
            const float4 wv = *(const float4*)(WL + k * 128 + 4 * cg);
            const float xr[4] = {xv.x, xv.y, xv.z, xv.w};
            const float wc[4] = {wv.x, wv.y, wv.z, wv.w};
            #pragma unroll
            for (int i = 0; i < 4; ++i)
                #pragma unroll
                for (int j = 0; j < 4; ++j)
                    acc[i][j] = fmaf(xr[i], wc[j], acc[i][j]);
        }
        __syncthreads();
    }
    #pragma unroll
    for (int i = 0; i < 4; ++i) {
        float4 v = make_float4(acc[i][0], acc[i][1], acc[i][2], acc[i][3]);
        *(float4*)(Y + (rbase + 4 * rg + i) * 128 + 4 * cg) = v;
    }
}

// ---------------- GEMM: Y[N,40] = X[N,128] @ W3[128,40] ----------------
// Block = 256 threads, tile = 64 rows; 2560 outputs/block = 10/thread.
__global__ __launch_bounds__(256) void k_gemm40(const float* __restrict__ X,
                                                const float* __restrict__ W,
                                                float* __restrict__ Y) {
    __shared__ float WL[128 * 40];    // 20 KB: [k][col]
    __shared__ float XL[64 * 132];    // 33.8 KB: [row][k], pad 132 (16B-aligned)
    const int t = threadIdx.x;
    const int rbase = blockIdx.x * 64;

    for (int i = t; i < 128 * 40; i += 256) WL[i] = W[i];
    #pragma unroll
    for (int i = 0; i < 8; ++i) {
        int j = t + 256 * i;          // 0..2047 float4s
        int row = j >> 5;             // 0..63
        int c4 = j & 31;              // float4 col
        float4 v = make_float4(0.f, 0.f, 0.f, 0.f);
        if (rbase + row < NN) v = *(const float4*)(X + (rbase + row) * 128 + 4 * c4);
        *(float4*)(XL + row * 132 + 4 * c4) = v;
    }
    __syncthreads();
    #pragma unroll
    for (int i = 0; i < 10; ++i) {
        int o = t + 256 * i;          // 0..2559
        int row = o / 40;
        int col = o - row * 40;
        float acc = 0.f;
        #pragma unroll 8
        for (int k = 0; k < 128; ++k)
            acc = fmaf(XL[row * 132 + k], WL[k * 40 + col], acc);
        if (rbase + row < NN) Y[(rbase + row) * 40 + col] = acc;
    }
}

// ---------------- aggregation ----------------
// init with self-loop contribution: agg[n][f] = xw[n][f] * dis[n]^2
template <int F>
__global__ __launch_bounds__(256) void k_scatter_init(const float* __restrict__ xw,
                                                      const float* __restrict__ dis,
                                                      float* __restrict__ agg) {
    int i = blockIdx.x * 256 + threadIdx.x;
    if (i < NN * F) {
        int n = i / F;
        float d = dis[n];
        agg[i] = xw[i] * d * d;
    }
}

template <int F>
__global__ __launch_bounds__(256) void k_scatter(const int* __restrict__ src,
                                                 const int* __restrict__ dst,
                                                 const float* __restrict__ nrm,
                                                 const float* __restrict__ xw,
                                                 float* __restrict__ agg) {
    int i = blockIdx.x * 256 + threadIdx.x;
    if (i < NE * F) {
        int e = i / F;
        int f = i - e * F;
        int s = src[e];
        int d = dst[e];
        atomicAdd(&agg[d * F + f], xw[s * F + f] * nrm[e]);
    }
}

template <int F>
__global__ __launch_bounds__(256) void k_bias_relu(float* __restrict__ x,
                                                   const float* __restrict__ b) {
    int i = blockIdx.x * 256 + threadIdx.x;
    if (i < NN * F) {
        int f = i % F;
        x[i] = fmaxf(x[i] + b[f], 0.f);
    }
}

// ---------------- fused bias + relu + log_softmax over 40 classes ----------------
// one wave (64 lanes) per row, lanes 0..39 active
__global__ __launch_bounds__(256) void k_lsm(const float* __restrict__ agg,
                                             const float* __restrict__ b,
                                             float* __restrict__ out) {
    int wave = threadIdx.x >> 6;
    int lane = threadIdx.x & 63;
    int row = blockIdx.x * 4 + wave;
    if (row >= NN) return;
    bool act = lane < 40;
    float x = 0.f, m = -1e30f;
    if (act) {
        x = fmaxf(agg[row * 40 + lane] + b[lane], 0.f);
        m = x;
    }
    #pragma unroll
    for (int o = 32; o; o >>= 1) m = fmaxf(m, __shfl_xor(m, o, 64));
    float e = act ? expf(x - m) : 0.f;
    #pragma unroll
    for (int o = 32; o; o >>= 1) e += __shfl_xor(e, o, 64);
    if (act) out[row * 40 + lane] = x - m - logf(e);
}

// ---------------- launch ----------------
extern "C" void kernel_launch(void* const* d_in, const int* in_sizes, int n_in,
                              void* d_out, int out_size, void* d_ws, size_t ws_size,
                              hipStream_t stream) {
    const float* feat = (const float*)d_in[0];
    const int* ei = (const int*)d_in[1];
    const float* W1 = (const float*)d_in[2];
    const float* b1 = (const float*)d_in[3];
    const float* W2 = (const float*)d_in[4];
    const float* b2 = (const float*)d_in[5];
    const float* W3 = (const float*)d_in[6];
    const float* b3 = (const float*)d_in[7];
    const int* src = ei;
    const int* dst = ei + NE;
    float* out = (float*)d_out;

    // workspace: dis[100032] | nrm[600064] | bufY[N*128] | bufX[N*128] | bufZ[N*128]
    // total ~156.4 MB
    float* dis = (float*)d_ws;
    float* nrm = dis + 100032;
    float* bufY = nrm + 600064;
    float* bufX = bufY + NN * 128;
    float* bufZ = bufX + NN * 128;

    const int B = 256;
    #define CDIV(a, b) (((a) + (b) - 1) / (b))

    // normalization (computed once, reused all layers)
    k_deg_init<<<CDIV(NN, B), B, 0, stream>>>(dis);
    k_deg_count<<<CDIV(NE, B), B, 0, stream>>>(dst, dis);
    k_dis<<<CDIV(NN, B), B, 0, stream>>>(dis);
    k_norm<<<CDIV(NE, B), B, 0, stream>>>(src, dst, dis, nrm);

    // layer 1: feat @ W1 -> Y; aggregate Y -> X; relu(X + b1)
    k_gemm128<<<NN / 32, B, 0, stream>>>(feat, W1, bufY);
    k_scatter_init<128><<<CDIV(NN * 128, B), B, 0, stream>>>(bufY, dis, bufX);
    k_scatter<128><<<CDIV(NE * 128, B), B, 0, stream>>>(src, dst, nrm, bufY, bufX);
    k_bias_relu<128><<<CDIV(NN * 128, B), B, 0, stream>>>(bufX, b1);

    // layer 2: X @ W2 -> Y; aggregate Y -> Z; relu(Z + b2)
    k_gemm128<<<NN / 32, B, 0, stream>>>(bufX, W2, bufY);
    k_scatter_init<128><<<CDIV(NN * 128, B), B, 0, stream>>>(bufY, dis, bufZ);
    k_scatter<128><<<CDIV(NE * 128, B), B, 0, stream>>>(src, dst, nrm, bufY, bufZ);
    k_bias_relu<128><<<CDIV(NN * 128, B), B, 0, stream>>>(bufZ, b2);

    // layer 3: Z @ W3 -> Y(40); aggregate Y -> X(40); fused bias+relu+log_softmax
    k_gemm40<<<CDIV(NN, 64), B, 0, stream>>>(bufZ, W3, bufY);
    k_scatter_init<40><<<CDIV(NN * 40, B), B, 0, stream>>>(bufY, dis, bufX);
    k_scatter<40><<<CDIV(NE * 40, B), B, 0, stream>>>(src, dst, nrm, bufY, bufX);
    k_lsm<<<CDIV(NN, 4), B, 0, stream>>>(bufX, b3, out);
    #undef CDIV
}

// Round 2
// 572.891 us; speedup vs baseline: 1.8240x; 1.8240x over previous
//
#include <hip/hip_runtime.h>
#include <hip/hip_bf16.h>

#define NN 100000   // nodes
#define NE 600000   // edges (before self-loops; self-loop handled analytically)
#define NBLK 391    // ceil(NN/256)

// ================= CSR build =================
__global__ __launch_bounds__(256) void k_cnt_init(int* __restrict__ cnt) {
    int i = blockIdx.x * 256 + threadIdx.x;
    if (i < NN) cnt[i] = 0;
}
__global__ __launch_bounds__(256) void k_cnt(const int* __restrict__ dst,
                                             int* __restrict__ cnt) {
    int e = blockIdx.x * 256 + threadIdx.x;
    if (e < NE) atomicAdd(&cnt[dst[e]], 1);
}
__global__ __launch_bounds__(256) void k_dis(const int* __restrict__ cnt,
                                             float* __restrict__ dis) {
    int i = blockIdx.x * 256 + threadIdx.x;
    if (i < NN) dis[i] = rsqrtf((float)(cnt[i] + 1));   // +1 self-loop
}
// per-block sums of cnt
__global__ __launch_bounds__(256) void k_blockred(const int* __restrict__ cnt,
                                                  int* __restrict__ blocksum) {
    int t = threadIdx.x;
    int i = blockIdx.x * 256 + t;
    int c = (i < NN) ? cnt[i] : 0;
    #pragma unroll
    for (int o = 32; o; o >>= 1) c += __shfl_xor(c, o, 64);
    __shared__ int ws[4];
    if ((t & 63) == 0) ws[t >> 6] = c;
    __syncthreads();
    if (t == 0) blocksum[blockIdx.x] = ws[0] + ws[1] + ws[2] + ws[3];
}
// exclusive scan of NBLK block sums (single block)
__global__ __launch_bounds__(256) void k_scanblk(const int* __restrict__ blocksum,
                                                 int* __restrict__ blockbase) {
    __shared__ int s[NBLK];
    int t = threadIdx.x;
    for (int i = t; i < NBLK; i += 256) s[i] = blocksum[i];
    __syncthreads();
    if (t == 0) {
        int run = 0;
        for (int i = 0; i < NBLK; ++i) { int v = s[i]; s[i] = run; run += v; }
    }
    __syncthreads();
    for (int i = t; i < NBLK; i += 256) blockbase[i] = s[i];
}
// per-element exclusive offsets = blockbase + in-block exclusive scan
__global__ __launch_bounds__(256) void k_offsets(const int* __restrict__ cnt,
                                                 const int* __restrict__ blockbase,
                                                 int* __restrict__ offsets,
                                                 int* __restrict__ cursor) {
    int t = threadIdx.x, lane = t & 63, wv = t >> 6;
    int i = blockIdx.x * 256 + t;
    int c = (i < NN) ? cnt[i] : 0;
    int x = c;  // inclusive wave scan
    #pragma unroll
    for (int o = 1; o < 64; o <<= 1) {
        int v = __shfl_up(x, o, 64);
        if (lane >= o) x += v;
    }
    __shared__ int wsum[4], wbase[4];
    if (lane == 63) wsum[wv] = x;
    __syncthreads();
    if (t == 0) {
        int run = 0;
        #pragma unroll
        for (int k = 0; k < 4; ++k) { wbase[k] = run; run += wsum[k]; }
    }
    __syncthreads();
    int excl = blockbase[blockIdx.x] + wbase[wv] + x - c;
    if (i < NN) {
        offsets[i] = excl;
        cursor[i] = excl;
        if (i == NN - 1) offsets[NN] = excl + c;
    }
}
// scatter edges into dst-buckets; precompute per-edge norm
__global__ __launch_bounds__(256) void k_fill(const int* __restrict__ src,
                                              const int* __restrict__ dst,
                                              const float* __restrict__ dis,
                                              int* __restrict__ cursor,
                                              int* __restrict__ srcs,
                                              float* __restrict__ nrmv) {
    int e = blockIdx.x * 256 + threadIdx.x;
    if (e < NE) {
        int s = src[e], d = dst[e];
        int pos = atomicAdd(&cursor[d], 1);
        srcs[pos] = s;
        nrmv[pos] = dis[s] * dis[d];
    }
}

// ================= GEMM: Y[N,128] = X[N,128] @ W[128,128] =================
__global__ __launch_bounds__(256) void k_gemm128(const float* __restrict__ X,
                                                 const float* __restrict__ W,
                                                 float* __restrict__ Y) {
    __shared__ float WL[64 * 128];
    __shared__ float XT[64 * 36];
    const int t = threadIdx.x;
    const int rbase = blockIdx.x * 32;
    const int cg = t & 31;
    const int rg = t >> 5;
    float acc[4][4] = {};

    for (int k0 = 0; k0 < 128; k0 += 64) {
        {
            const float4* Wg = (const float4*)(W + k0 * 128);
            float4* Ws = (float4*)WL;
            #pragma unroll
            for (int i = 0; i < 8; ++i) Ws[t + 256 * i] = Wg[t + 256 * i];
        }
        {
            int r = t >> 6;
            int k = t & 63;
            #pragma unroll
            for (int i = 0; i < 8; ++i)
                XT[k * 36 + (r + 4 * i)] = X[(rbase + r + 4 * i) * 128 + k0 + k];
        }
        __syncthreads();
        #pragma unroll 8
        for (int k = 0; k < 64; ++k) {
            const float4 xv = *(const float4*)(XT + k * 36 + 4 * rg);
            const float4 wv = *(const float4*)(WL + k * 128 + 4 * cg);
            const float xr[4] = {xv.x, xv.y, xv.z, xv.w};
            const float wc[4] = {wv.x, wv.y, wv.z, wv.w};
            #pragma unroll
            for (int i = 0; i < 4; ++i)
                #pragma unroll
                for (int j = 0; j < 4; ++j)
                    acc[i][j] = fmaf(xr[i], wc[j], acc[i][j]);
        }
        __syncthreads();
    }
    #pragma unroll
    for (int i = 0; i < 4; ++i) {
        float4 v = make_float4(acc[i][0], acc[i][1], acc[i][2], acc[i][3]);
        *(float4*)(Y + (rbase + 4 * rg + i) * 128 + 4 * cg) = v;
    }
}

// ================= GEMM: Y[N,40] = X[N,128] @ W3[128,40] =================
__global__ __launch_bounds__(256) void k_gemm40(const float* __restrict__ X,
                                                const float* __restrict__ W,
                                                float* __restrict__ Y) {
    __shared__ float WL[128 * 40];
    __shared__ float XL[64 * 132];
    const int t = threadIdx.x;
    const int rbase = blockIdx.x * 64;

    for (int i = t; i < 128 * 40; i += 256) WL[i] = W[i];
    #pragma unroll
    for (int i = 0; i < 8; ++i) {
        int j = t + 256 * i;
        int row = j >> 5;
        int c4 = j & 31;
        float4 v = make_float4(0.f, 0.f, 0.f, 0.f);
        if (rbase + row < NN) v = *(const float4*)(X + (rbase + row) * 128 + 4 * c4);
        *(float4*)(XL + row * 132 + 4 * c4) = v;
    }
    __syncthreads();
    #pragma unroll
    for (int i = 0; i < 10; ++i) {
        int o = t + 256 * i;
        int row = o / 40;
        int col = o - row * 40;
        float acc = 0.f;
        #pragma unroll 8
        for (int k = 0; k < 128; ++k)
            acc = fmaf(XL[row * 132 + k], WL[k * 40 + col], acc);
        if (rbase + row < NN) Y[(rbase + row) * 40 + col] = acc;
    }
}

// ================= fused aggregate (CSR gather) + bias + relu, F=128 =================
// one wave per node; lane holds float2 (features 2*lane, 2*lane+1)
__global__ __launch_bounds__(256) void k_agg128(const int* __restrict__ offsets,
                                                const int* __restrict__ srcs,
                                                const float* __restrict__ nrmv,
                                                const float* __restrict__ dis,
                                                const float* __restrict__ xw,
                                                const float* __restrict__ bias,
                                                float* __restrict__ out) {
    int wv = threadIdx.x >> 6, lane = threadIdx.x & 63;
    int n = blockIdx.x * 4 + wv;
    if (n >= NN) return;
    int beg = offsets[n], end = offsets[n + 1];
    float d = dis[n];
    float2 acc = ((const float2*)(xw + n * 128))[lane];
    acc.x *= d * d;
    acc.y *= d * d;
    for (int j = beg; j < end; ++j) {
        int s = srcs[j];
        float w = nrmv[j];
        float2 v = ((const float2*)(xw + s * 128))[lane];
        acc.x = fmaf(v.x, w, acc.x);
        acc.y = fmaf(v.y, w, acc.y);
    }
    float2 bv = ((const float2*)bias)[lane];
    acc.x = fmaxf(acc.x + bv.x, 0.f);
    acc.y = fmaxf(acc.y + bv.y, 0.f);
    ((float2*)(out + n * 128))[lane] = acc;
}

// ================= fused aggregate + bias + relu + log_softmax, F=40 =================
__global__ __launch_bounds__(256) void k_agg40_lsm(const int* __restrict__ offsets,
                                                   const int* __restrict__ srcs,
                                                   const float* __restrict__ nrmv,
                                                   const float* __restrict__ dis,
                                                   const float* __restrict__ xw,
                                                   const float* __restrict__ bias,
                                                   float* __restrict__ out) {
    int wv = threadIdx.x >> 6, lane = threadIdx.x & 63;
    int n = blockIdx.x * 4 + wv;
    if (n >= NN) return;
    bool act = lane < 40;
    int beg = offsets[n], end = offsets[n + 1];
    float d = dis[n];
    float x = 0.f;
    if (act) x = xw[n * 40 + lane] * d * d;
    for (int j = beg; j < end; ++j) {
        int s = srcs[j];
        float w = nrmv[j];
        if (act) x = fmaf(xw[s * 40 + lane], w, x);
    }
    if (act) x = fmaxf(x + bias[lane], 0.f);
    float m = act ? x : -1e30f;
    #pragma unroll
    for (int o = 32; o; o >>= 1) m = fmaxf(m, __shfl_xor(m, o, 64));
    float e = act ? expf(x - m) : 0.f;
    #pragma unroll
    for (int o = 32; o; o >>= 1) e += __shfl_xor(e, o, 64);
    if (act) out[n * 40 + lane] = x - m - logf(e);
}

// ================= launch =================
extern "C" void kernel_launch(void* const* d_in, const int* in_sizes, int n_in,
                              void* d_out, int out_size, void* d_ws, size_t ws_size,
                              hipStream_t stream) {
    const float* feat = (const float*)d_in[0];
    const int* ei = (const int*)d_in[1];
    const float* W1 = (const float*)d_in[2];
    const float* b1 = (const float*)d_in[3];
    const float* W2 = (const float*)d_in[4];
    const float* b2 = (const float*)d_in[5];
    const float* W3 = (const float*)d_in[6];
    const float* b3 = (const float*)d_in[7];
    const int* src = ei;
    const int* dst = ei + NE;
    float* out = (float*)d_out;

    // workspace layout (all 4B elems, padded to 256-elem boundaries)
    char* w = (char*)d_ws;
    int* cnt = (int*)w;              w += 100352 * 4;
    float* dis = (float*)w;          w += 100352 * 4;
    int* offsets = (int*)w;          w += 100608 * 4;
    int* cursor = (int*)w;           w += 100352 * 4;
    int* blocksum = (int*)w;         w += 512 * 4;
    int* blockbase = (int*)w;        w += 512 * 4;
    int* srcs = (int*)w;             w += 600064 * 4;
    float* nrmv = (float*)w;         w += 600064 * 4;
    float* bufA = (float*)w;         w += (size_t)NN * 128 * 4;
    float* bufB = (float*)w;

    const int B = 256;
    #define CDIV(a, b) (((a) + (b) - 1) / (b))

    // ---- CSR build (once; reused by all layers) ----
    k_cnt_init<<<NBLK, B, 0, stream>>>(cnt);
    k_cnt<<<CDIV(NE, B), B, 0, stream>>>(dst, cnt);
    k_dis<<<NBLK, B, 0, stream>>>(cnt, dis);
    k_blockred<<<NBLK, B, 0, stream>>>(cnt, blocksum);
    k_scanblk<<<1, B, 0, stream>>>(blocksum, blockbase);
    k_offsets<<<NBLK, B, 0, stream>>>(cnt, blockbase, offsets, cursor);
    k_fill<<<CDIV(NE, B), B, 0, stream>>>(src, dst, dis, cursor, srcs, nrmv);

    // ---- layer 1 ----
    k_gemm128<<<NN / 32, B, 0, stream>>>(feat, W1, bufA);
    k_agg128<<<CDIV(NN, 4), B, 0, stream>>>(offsets, srcs, nrmv, dis, bufA, b1, bufB);
    // ---- layer 2 ----
    k_gemm128<<<NN / 32, B, 0, stream>>>(bufB, W2, bufA);
    k_agg128<<<CDIV(NN, 4), B, 0, stream>>>(offsets, srcs, nrmv, dis, bufA, b2, bufB);
    // ---- layer 3 ----
    k_gemm40<<<CDIV(NN, 64), B, 0, stream>>>(bufB, W3, bufA);
    k_agg40_lsm<<<CDIV(NN, 4), B, 0, stream>>>(offsets, srcs, nrmv, dis, bufA, b3, out);
    #undef CDIV
}

// Round 3
// 427.116 us; speedup vs baseline: 2.4465x; 1.3413x over previous
//
#include <hip/hip_runtime.h>
#include <hip/hip_bf16.h>

#define NN 100000   // nodes
#define NE 600000   // edges (self-loop handled analytically)
#define NBLK 391    // ceil(NN/256)
#define NPAD 100096 // row padding for 128-row GEMM tiles

typedef unsigned int uint;
typedef unsigned short ushort;
typedef __attribute__((ext_vector_type(8))) short bf16x8;
typedef __attribute__((ext_vector_type(4))) float f32x4;

__device__ __forceinline__ ushort f2b(float f) {
    union { float f; uint u; } v; v.f = f;
    return (ushort)((v.u + 0x7fffu + ((v.u >> 16) & 1u)) >> 16);
}
__device__ __forceinline__ float b2f(uint h) {
    union { uint u; float f; } v; v.u = h << 16; return v.f;
}

// ================= CSR build =================
__global__ __launch_bounds__(256) void k_cnt_init(int* __restrict__ cnt) {
    int i = blockIdx.x * 256 + threadIdx.x;
    if (i < NN) cnt[i] = 0;
}
__global__ __launch_bounds__(256) void k_cnt(const int* __restrict__ dst,
                                             int* __restrict__ cnt) {
    int e = blockIdx.x * 256 + threadIdx.x;
    if (e < NE) atomicAdd(&cnt[dst[e]], 1);
}
__global__ __launch_bounds__(256) void k_dis(const int* __restrict__ cnt,
                                             float* __restrict__ dis) {
    int i = blockIdx.x * 256 + threadIdx.x;
    if (i < NN) dis[i] = rsqrtf((float)(cnt[i] + 1));
}
__global__ __launch_bounds__(256) void k_blockred(const int* __restrict__ cnt,
                                                  int* __restrict__ blocksum) {
    int t = threadIdx.x;
    int i = blockIdx.x * 256 + t;
    int c = (i < NN) ? cnt[i] : 0;
    #pragma unroll
    for (int o = 32; o; o >>= 1) c += __shfl_xor(c, o, 64);
    __shared__ int ws[4];
    if ((t & 63) == 0) ws[t >> 6] = c;
    __syncthreads();
    if (t == 0) blocksum[blockIdx.x] = ws[0] + ws[1] + ws[2] + ws[3];
}
__global__ __launch_bounds__(256) void k_scanblk(const int* __restrict__ blocksum,
                                                 int* __restrict__ blockbase) {
    __shared__ int s[NBLK];
    int t = threadIdx.x;
    for (int i = t; i < NBLK; i += 256) s[i] = blocksum[i];
    __syncthreads();
    if (t == 0) {
        int run = 0;
        for (int i = 0; i < NBLK; ++i) { int v = s[i]; s[i] = run; run += v; }
    }
    __syncthreads();
    for (int i = t; i < NBLK; i += 256) blockbase[i] = s[i];
}
__global__ __launch_bounds__(256) void k_offsets(const int* __restrict__ cnt,
                                                 const int* __restrict__ blockbase,
                                                 int* __restrict__ offsets,
                                                 int* __restrict__ cursor) {
    int t = threadIdx.x, lane = t & 63, wv = t >> 6;
    int i = blockIdx.x * 256 + t;
    int c = (i < NN) ? cnt[i] : 0;
    int x = c;
    #pragma unroll
    for (int o = 1; o < 64; o <<= 1) {
        int v = __shfl_up(x, o, 64);
        if (lane >= o) x += v;
    }
    __shared__ int wsum[4], wbase[4];
    if (lane == 63) wsum[wv] = x;
    __syncthreads();
    if (t == 0) {
        int run = 0;
        #pragma unroll
        for (int k = 0; k < 4; ++k) { wbase[k] = run; run += wsum[k]; }
    }
    __syncthreads();
    int excl = blockbase[blockIdx.x] + wbase[wv] + x - c;
    if (i < NN) {
        offsets[i] = excl;
        cursor[i] = excl;
        if (i == NN - 1) offsets[NN] = excl + c;
    }
}
__global__ __launch_bounds__(256) void k_fill(const int* __restrict__ src,
                                              const int* __restrict__ dst,
                                              const float* __restrict__ dis,
                                              int* __restrict__ cursor,
                                              int* __restrict__ srcs,
                                              float* __restrict__ nrmv) {
    int e = blockIdx.x * 256 + threadIdx.x;
    if (e < NE) {
        int s = src[e], d = dst[e];
        int pos = atomicAdd(&cursor[d], 1);
        srcs[pos] = s;
        nrmv[pos] = dis[s] * dis[d];
    }
}

// ================= casts =================
__global__ __launch_bounds__(256) void k_castX(const float* __restrict__ X,
                                               ushort* __restrict__ Xb) {
    int i = blockIdx.x * 256 + threadIdx.x;   // 4 elems each
    if (i < NN * 32) {
        float4 v = ((const float4*)X)[i];
        ushort4 o;
        o.x = f2b(v.x); o.y = f2b(v.y); o.z = f2b(v.z); o.w = f2b(v.w);
        ((ushort4*)Xb)[i] = o;
    }
}
// W[K=128][ncols] fp32 -> WT[npad][128] bf16, zero-padded cols
__global__ __launch_bounds__(256) void k_castWT(const float* __restrict__ W,
                                                ushort* __restrict__ WT, int ncols,
                                                int npad) {
    int o = blockIdx.x * 256 + threadIdx.x;
    if (o < npad * 128) {
        int n = o >> 7, k = o & 127;
        float v = (n < ncols) ? W[k * ncols + n] : 0.f;
        WT[o] = f2b(v);
    }
}

// ================= MFMA GEMM: Y[N,128] = X[N,128] @ W, bf16 in/out =================
// block tile 64 rows x 128 cols; wave = 16 rows x 128 cols (8 col-tiles), K=128
__global__ __launch_bounds__(256) void k_gemm128b(const ushort* __restrict__ Xb,
                                                  const ushort* __restrict__ WT,
                                                  ushort* __restrict__ Yb) {
    __shared__ ushort AL[64 * 136];    // +8 pad: 2-way LDS aliasing only
    __shared__ ushort BL[128 * 136];
    const int t = threadIdx.x;
    const int rbase = blockIdx.x * 64;
    // stage B = W^T [n][k], whole matrix (2048 16B chunks)
    #pragma unroll
    for (int i = 0; i < 8; ++i) {
        int ch = t + 256 * i;
        int n = ch >> 4, c = ch & 15;
        *(int4*)(BL + n * 136 + c * 8) = *(const int4*)(WT + n * 128 + c * 8);
    }
    // stage A rows rbase..rbase+63 (1024 chunks)
    #pragma unroll
    for (int i = 0; i < 4; ++i) {
        int ch = t + 256 * i;
        int m = ch >> 4, c = ch & 15;
        *(int4*)(AL + m * 136 + c * 8) =
            *(const int4*)(Xb + (size_t)(rbase + m) * 128 + c * 8);
    }
    __syncthreads();
    const int wv = t >> 6, l = t & 63;
    const int m16 = l & 15, q = l >> 4;
    f32x4 acc[8];
    #pragma unroll
    for (int j = 0; j < 8; ++j) acc[j] = (f32x4){0.f, 0.f, 0.f, 0.f};
    #pragma unroll
    for (int kt = 0; kt < 4; ++kt) {
        bf16x8 a = *(const bf16x8*)(AL + (wv * 16 + m16) * 136 + kt * 32 + q * 8);
        bf16x8 b[8];
        #pragma unroll
        for (int j = 0; j < 8; ++j)
            b[j] = *(const bf16x8*)(BL + (j * 16 + m16) * 136 + kt * 32 + q * 8);
        #pragma unroll
        for (int j = 0; j < 8; ++j)
            acc[j] = __builtin_amdgcn_mfma_f32_16x16x32_bf16(a, b[j], acc[j], 0, 0, 0);
    }
    // D: row = q*4+r, col = j*16 + m16
    #pragma unroll
    for (int r = 0; r < 4; ++r) {
        int row = rbase + wv * 16 + q * 4 + r;
        if (row < NN) {
            #pragma unroll
            for (int j = 0; j < 8; ++j)
                Yb[(size_t)row * 128 + j * 16 + m16] = f2b(acc[j][r]);
        }
    }
}

// ================= MFMA GEMM: Y[N,40] = X[N,128] @ W3 (N pad 48) =================
// block tile 128 rows x 48 cols; wave = 32 rows (2 tiles) x 48 cols (3 tiles)
__global__ __launch_bounds__(256) void k_gemm40b(const ushort* __restrict__ Xb,
                                                 const ushort* __restrict__ W3T,
                                                 ushort* __restrict__ Yb) {
    __shared__ ushort AL[128 * 136];
    __shared__ ushort BL[48 * 136];
    const int t = threadIdx.x;
    const int rbase = blockIdx.x * 128;
    #pragma unroll
    for (int i = 0; i < 3; ++i) {   // 768 chunks
        int ch = t + 256 * i;
        int n = ch >> 4, c = ch & 15;
        *(int4*)(BL + n * 136 + c * 8) = *(const int4*)(W3T + n * 128 + c * 8);
    }
    #pragma unroll
    for (int i = 0; i < 8; ++i) {   // 2048 chunks
        int ch = t + 256 * i;
        int m = ch >> 4, c = ch & 15;
        *(int4*)(AL + m * 136 + c * 8) =
            *(const int4*)(Xb + (size_t)(rbase + m) * 128 + c * 8);
    }
    __syncthreads();
    const int wv = t >> 6, l = t & 63;
    const int m16 = l & 15, q = l >> 4;
    f32x4 acc[2][3];
    #pragma unroll
    for (int i = 0; i < 2; ++i)
        #pragma unroll
        for (int j = 0; j < 3; ++j) acc[i][j] = (f32x4){0.f, 0.f, 0.f, 0.f};
    #pragma unroll
    for (int kt = 0; kt < 4; ++kt) {
        bf16x8 a[2], b[3];
        #pragma unroll
        for (int i = 0; i < 2; ++i)
            a[i] = *(const bf16x8*)(AL + ((wv * 2 + i) * 16 + m16) * 136 + kt * 32 + q * 8);
        #pragma unroll
        for (int j = 0; j < 3; ++j)
            b[j] = *(const bf16x8*)(BL + (j * 16 + m16) * 136 + kt * 32 + q * 8);
        #pragma unroll
        for (int i = 0; i < 2; ++i)
            #pragma unroll
            for (int j = 0; j < 3; ++j)
                acc[i][j] = __builtin_amdgcn_mfma_f32_16x16x32_bf16(a[i], b[j], acc[i][j], 0, 0, 0);
    }
    #pragma unroll
    for (int i = 0; i < 2; ++i) {
        #pragma unroll
        for (int r = 0; r < 4; ++r) {
            int row = rbase + (wv * 2 + i) * 16 + q * 4 + r;
            if (row < NN) {
                #pragma unroll
                for (int j = 0; j < 3; ++j) {
                    int col = j * 16 + m16;
                    if (col < 40) Yb[(size_t)row * 40 + col] = f2b(acc[i][j][r]);
                }
            }
        }
    }
}

// ================= fused aggregate + bias + relu, F=128, bf16 io =================
__global__ __launch_bounds__(256) void k_agg128b(const int* __restrict__ offsets,
                                                 const int* __restrict__ srcs,
                                                 const float* __restrict__ nrmv,
                                                 const float* __restrict__ dis,
                                                 const ushort* __restrict__ xw,
                                                 const float* __restrict__ bias,
                                                 ushort* __restrict__ out) {
    int wv = threadIdx.x >> 6, lane = threadIdx.x & 63;
    int n = blockIdx.x * 4 + wv;
    if (n >= NN) return;
    int beg = offsets[n], end = offsets[n + 1];
    float d = dis[n];
    uint v0 = ((const uint*)(xw + (size_t)n * 128))[lane];
    float ax = b2f(v0 & 0xffffu) * d * d;
    float ay = b2f(v0 >> 16) * d * d;
    for (int j = beg; j < end; ++j) {
        int s = srcs[j];
        float w = nrmv[j];
        uint v = ((const uint*)(xw + (size_t)s * 128))[lane];
        ax = fmaf(b2f(v & 0xffffu), w, ax);
        ay = fmaf(b2f(v >> 16), w, ay);
    }
    float2 bv = ((const float2*)bias)[lane];
    ax = fmaxf(ax + bv.x, 0.f);
    ay = fmaxf(ay + bv.y, 0.f);
    uint o = (uint)f2b(ax) | ((uint)f2b(ay) << 16);
    ((uint*)(out + (size_t)n * 128))[lane] = o;
}

// ================= fused aggregate + bias + relu + log_softmax, F=40 =================
__global__ __launch_bounds__(256) void k_agg40_lsm(const int* __restrict__ offsets,
                                                   const int* __restrict__ srcs,
                                                   const float* __restrict__ nrmv,
                                                   const float* __restrict__ dis,
                                                   const ushort* __restrict__ xw,
                                                   const float* __restrict__ bias,
                                                   float* __restrict__ out) {
    int wv = threadIdx.x >> 6, lane = threadIdx.x & 63;
    int n = blockIdx.x * 4 + wv;
    if (n >= NN) return;
    bool act = lane < 40;
    int beg = offsets[n], end = offsets[n + 1];
    float d = dis[n];
    float x = 0.f;
    if (act) x = b2f(xw[(size_t)n * 40 + lane]) * d * d;
    for (int j = beg; j < end; ++j) {
        int s = srcs[j];
        float w = nrmv[j];
        if (act) x = fmaf(b2f(xw[(size_t)s * 40 + lane]), w, x);
    }
    if (act) x = fmaxf(x + bias[lane], 0.f);
    float m = act ? x : -1e30f;
    #pragma unroll
    for (int o = 32; o; o >>= 1) m = fmaxf(m, __shfl_xor(m, o, 64));
    float e = act ? expf(x - m) : 0.f;
    #pragma unroll
    for (int o = 32; o; o >>= 1) e += __shfl_xor(e, o, 64);
    if (act) out[(size_t)n * 40 + lane] = x - m - logf(e);
}

// ================= launch =================
extern "C" void kernel_launch(void* const* d_in, const int* in_sizes, int n_in,
                              void* d_out, int out_size, void* d_ws, size_t ws_size,
                              hipStream_t stream) {
    const float* feat = (const float*)d_in[0];
    const int* ei = (const int*)d_in[1];
    const float* W1 = (const float*)d_in[2];
    const float* b1 = (const float*)d_in[3];
    const float* W2 = (const float*)d_in[4];
    const float* b2 = (const float*)d_in[5];
    const float* W3 = (const float*)d_in[6];
    const float* b3 = (const float*)d_in[7];
    const int* src = ei;
    const int* dst = ei + NE;
    float* out = (float*)d_out;

    char* w = (char*)d_ws;
    int* cnt = (int*)w;        w += 100352 * 4;
    float* dis = (float*)w;    w += 100352 * 4;
    int* offsets = (int*)w;    w += 100608 * 4;
    int* cursor = (int*)w;     w += 100352 * 4;
    int* blocksum = (int*)w;   w += 512 * 4;
    int* blockbase = (int*)w;  w += 512 * 4;
    int* srcs = (int*)w;       w += 600064 * 4;
    float* nrmv = (float*)w;   w += 600064 * 4;
    ushort* W1T = (ushort*)w;  w += 16384 * 2;
    ushort* W2T = (ushort*)w;  w += 16384 * 2;
    ushort* W3T = (ushort*)w;  w += 6144 * 2;
    ushort* featb = (ushort*)w; w += (size_t)NPAD * 128 * 2;
    ushort* bufYb = (ushort*)w; w += (size_t)NPAD * 128 * 2;
    ushort* bufXb = (ushort*)w; w += (size_t)NPAD * 128 * 2;
    ushort* Y40b = (ushort*)w;  w += (size_t)NPAD * 40 * 2;

    const int B = 256;
    #define CDIV(a, b) (((a) + (b) - 1) / (b))

    // CSR build (reused by all layers)
    k_cnt_init<<<NBLK, B, 0, stream>>>(cnt);
    k_cnt<<<CDIV(NE, B), B, 0, stream>>>(dst, cnt);
    k_dis<<<NBLK, B, 0, stream>>>(cnt, dis);
    k_blockred<<<NBLK, B, 0, stream>>>(cnt, blocksum);
    k_scanblk<<<1, B, 0, stream>>>(blocksum, blockbase);
    k_offsets<<<NBLK, B, 0, stream>>>(cnt, blockbase, offsets, cursor);
    k_fill<<<CDIV(NE, B), B, 0, stream>>>(src, dst, dis, cursor, srcs, nrmv);

    // casts
    k_castX<<<CDIV(NN * 32, B), B, 0, stream>>>(feat, featb);
    k_castWT<<<CDIV(128 * 128, B), B, 0, stream>>>(W1, W1T, 128, 128);
    k_castWT<<<CDIV(128 * 128, B), B, 0, stream>>>(W2, W2T, 128, 128);
    k_castWT<<<CDIV(48 * 128, B), B, 0, stream>>>(W3, W3T, 40, 48);

    // layer 1
    k_gemm128b<<<CDIV(NN, 64), B, 0, stream>>>(featb, W1T, bufYb);
    k_agg128b<<<CDIV(NN, 4), B, 0, stream>>>(offsets, srcs, nrmv, dis, bufYb, b1, bufXb);
    // layer 2
    k_gemm128b<<<CDIV(NN, 64), B, 0, stream>>>(bufXb, W2T, bufYb);
    k_agg128b<<<CDIV(NN, 4), B, 0, stream>>>(offsets, srcs, nrmv, dis, bufYb, b2, bufXb);
    // layer 3
    k_gemm40b<<<CDIV(NN, 128), B, 0, stream>>>(bufXb, W3T, Y40b);
    k_agg40_lsm<<<CDIV(NN, 4), B, 0, stream>>>(offsets, srcs, nrmv, dis, Y40b, b3, out);
    #undef CDIV
}

// Round 4
// 303.847 us; speedup vs baseline: 3.4390x; 1.4057x over previous
//
#include <hip/hip_runtime.h>
#include <hip/hip_bf16.h>

#define NN 100000   // nodes
#define NE 600000   // edges (self-loop handled analytically)
#define NBLK 391    // ceil(NN/256)
#define NPAD 100096 // row padding for 128-row GEMM tiles

typedef unsigned int uint;
typedef unsigned short ushort;
typedef __attribute__((ext_vector_type(8))) short bf16x8;
typedef __attribute__((ext_vector_type(4))) float f32x4;

__device__ __forceinline__ ushort f2b(float f) {
    union { float f; uint u; } v; v.f = f;
    return (ushort)((v.u + 0x7fffu + ((v.u >> 16) & 1u)) >> 16);
}
__device__ __forceinline__ float b2f(uint h) {
    union { uint u; float f; } v; v.u = h << 16; return v.f;
}

// ================= CSR build =================
__global__ __launch_bounds__(256) void k_cnt_init(int* __restrict__ cnt) {
    int i = blockIdx.x * 256 + threadIdx.x;
    if (i < NN) cnt[i] = 0;
}
__global__ __launch_bounds__(256) void k_cnt(const int* __restrict__ dst,
                                             int* __restrict__ cnt) {
    int e = blockIdx.x * 256 + threadIdx.x;
    if (e < NE) atomicAdd(&cnt[dst[e]], 1);
}
__global__ __launch_bounds__(256) void k_blockred(const int* __restrict__ cnt,
                                                  int* __restrict__ blocksum) {
    int t = threadIdx.x;
    int i = blockIdx.x * 256 + t;
    int c = (i < NN) ? cnt[i] : 0;
    #pragma unroll
    for (int o = 32; o; o >>= 1) c += __shfl_xor(c, o, 64);
    __shared__ int ws[4];
    if ((t & 63) == 0) ws[t >> 6] = c;
    __syncthreads();
    if (t == 0) blocksum[blockIdx.x] = ws[0] + ws[1] + ws[2] + ws[3];
}
__global__ __launch_bounds__(256) void k_scanblk(const int* __restrict__ blocksum,
                                                 int* __restrict__ blockbase) {
    __shared__ int s[NBLK];
    int t = threadIdx.x;
    for (int i = t; i < NBLK; i += 256) s[i] = blocksum[i];
    __syncthreads();
    if (t == 0) {
        int run = 0;
        for (int i = 0; i < NBLK; ++i) { int v = s[i]; s[i] = run; run += v; }
    }
    __syncthreads();
    for (int i = t; i < NBLK; i += 256) blockbase[i] = s[i];
}
// offsets + cursor + dis (fused)
__global__ __launch_bounds__(256) void k_offsets(const int* __restrict__ cnt,
                                                 const int* __restrict__ blockbase,
                                                 int* __restrict__ offsets,
                                                 int* __restrict__ cursor,
                                                 float* __restrict__ dis) {
    int t = threadIdx.x, lane = t & 63, wv = t >> 6;
    int i = blockIdx.x * 256 + t;
    int c = (i < NN) ? cnt[i] : 0;
    int x = c;
    #pragma unroll
    for (int o = 1; o < 64; o <<= 1) {
        int v = __shfl_up(x, o, 64);
        if (lane >= o) x += v;
    }
    __shared__ int wsum[4], wbase[4];
    if (lane == 63) wsum[wv] = x;
    __syncthreads();
    if (t == 0) {
        int run = 0;
        #pragma unroll
        for (int k = 0; k < 4; ++k) { wbase[k] = run; run += wsum[k]; }
    }
    __syncthreads();
    int excl = blockbase[blockIdx.x] + wbase[wv] + x - c;
    if (i < NN) {
        offsets[i] = excl;
        cursor[i] = excl;
        dis[i] = rsqrtf((float)(c + 1));
        if (i == NN - 1) offsets[NN] = excl + c;
    }
}
// bucket-fill packed edges {src, norm}
__global__ __launch_bounds__(256) void k_fill(const int* __restrict__ src,
                                              const int* __restrict__ dst,
                                              const float* __restrict__ dis,
                                              int* __restrict__ cursor,
                                              int2* __restrict__ edges) {
    int e = blockIdx.x * 256 + threadIdx.x;
    if (e < NE) {
        int s = src[e], d = dst[e];
        int pos = atomicAdd(&cursor[d], 1);
        float nr = dis[s] * dis[d];
        edges[pos] = make_int2(s, __float_as_int(nr));
    }
}

// ================= weight casts (all three in one kernel) =================
// WTall layout: W1T[128x128] | W2T[128x128] | W3T[48x128]  (each [n][k], bf16)
__global__ __launch_bounds__(256) void k_castW(const float* __restrict__ W1,
                                               const float* __restrict__ W2,
                                               const float* __restrict__ W3,
                                               ushort* __restrict__ WTall) {
    int o = blockIdx.x * 256 + threadIdx.x;
    if (o >= 38912) return;
    float v;
    if (o < 32768) {
        const float* W = (o < 16384) ? W1 : W2;
        int off = o & 16383;
        int n = off >> 7, k = off & 127;
        v = W[k * 128 + n];
    } else {
        int off = o - 32768;
        int n = off >> 7, k = off & 127;
        v = (n < 40) ? W3[k * 40 + n] : 0.f;
    }
    WTall[o] = f2b(v);
}

// ================= MFMA GEMM: Y[N,128] = X[N,128] @ W, K=128 =================
// block tile 64 rows x 128 cols; wave = 16 rows x 128 cols (8 col-tiles)
// F32IN: layer 1 reads fp32 features directly (fused cast)
template <bool F32IN>
__global__ __launch_bounds__(256) void k_gemm128b(const void* __restrict__ Xin,
                                                  const ushort* __restrict__ WT,
                                                  ushort* __restrict__ Yb) {
    __shared__ ushort AL[64 * 136];    // +8 pad: 2-way LDS aliasing only (free)
    __shared__ ushort BL[128 * 136];
    const int t = threadIdx.x;
    const int rbase = blockIdx.x * 64;
    // stage B = W^T [n][k] whole (2048 16B chunks)
    #pragma unroll
    for (int i = 0; i < 8; ++i) {
        int ch = t + 256 * i;
        int n = ch >> 4, c = ch & 15;
        *(int4*)(BL + n * 136 + c * 8) = *(const int4*)(WT + n * 128 + c * 8);
    }
    // stage A rows rbase..rbase+63 (1024 chunks of 8 elems)
    #pragma unroll
    for (int i = 0; i < 4; ++i) {
        int ch = t + 256 * i;
        int m = ch >> 4, c = ch & 15;
        int row = min(rbase + m, NN - 1);   // clamp: last block reads in-bounds
        if (F32IN) {
            const float* Xf = (const float*)Xin;
            float4 f0 = *(const float4*)(Xf + (size_t)row * 128 + c * 8);
            float4 f1 = *(const float4*)(Xf + (size_t)row * 128 + c * 8 + 4);
            ushort* p = AL + m * 136 + c * 8;
            p[0] = f2b(f0.x); p[1] = f2b(f0.y); p[2] = f2b(f0.z); p[3] = f2b(f0.w);
            p[4] = f2b(f1.x); p[5] = f2b(f1.y); p[6] = f2b(f1.z); p[7] = f2b(f1.w);
        } else {
            const ushort* Xb = (const ushort*)Xin;
            *(int4*)(AL + m * 136 + c * 8) =
                *(const int4*)(Xb + (size_t)row * 128 + c * 8);
        }
    }
    __syncthreads();
    const int wv = t >> 6, l = t & 63;
    const int m16 = l & 15, q = l >> 4;
    f32x4 acc[8];
    #pragma unroll
    for (int j = 0; j < 8; ++j) acc[j] = (f32x4){0.f, 0.f, 0.f, 0.f};
    #pragma unroll
    for (int kt = 0; kt < 4; ++kt) {
        bf16x8 a = *(const bf16x8*)(AL + (wv * 16 + m16) * 136 + kt * 32 + q * 8);
        #pragma unroll
        for (int j = 0; j < 8; ++j) {
            bf16x8 b = *(const bf16x8*)(BL + (j * 16 + m16) * 136 + kt * 32 + q * 8);
            acc[j] = __builtin_amdgcn_mfma_f32_16x16x32_bf16(a, b, acc[j], 0, 0, 0);
        }
    }
    #pragma unroll
    for (int r = 0; r < 4; ++r) {
        int row = rbase + wv * 16 + q * 4 + r;
        if (row < NN) {
            #pragma unroll
            for (int j = 0; j < 8; ++j)
                Yb[(size_t)row * 128 + j * 16 + m16] = f2b(acc[j][r]);
        }
    }
}

// ================= MFMA GEMM: Y[N,48pad64] = X[N,128] @ W3 =================
// block tile 128 rows x 48 cols; wave = 32 rows (2 m-tiles) x 48 cols (3 n-tiles)
__global__ __launch_bounds__(256) void k_gemm40b(const ushort* __restrict__ Xb,
                                                 const ushort* __restrict__ W3T,
                                                 ushort* __restrict__ Yb) {
    __shared__ ushort AL[128 * 136];
    __shared__ ushort BL[48 * 136];
    const int t = threadIdx.x;
    const int rbase = blockIdx.x * 128;
    #pragma unroll
    for (int i = 0; i < 3; ++i) {
        int ch = t + 256 * i;
        int n = ch >> 4, c = ch & 15;
        *(int4*)(BL + n * 136 + c * 8) = *(const int4*)(W3T + n * 128 + c * 8);
    }
    #pragma unroll
    for (int i = 0; i < 8; ++i) {
        int ch = t + 256 * i;
        int m = ch >> 4, c = ch & 15;
        *(int4*)(AL + m * 136 + c * 8) =
            *(const int4*)(Xb + (size_t)(rbase + m) * 128 + c * 8);
    }
    __syncthreads();
    const int wv = t >> 6, l = t & 63;
    const int m16 = l & 15, q = l >> 4;
    f32x4 acc[2][3];
    #pragma unroll
    for (int i = 0; i < 2; ++i)
        #pragma unroll
        for (int j = 0; j < 3; ++j) acc[i][j] = (f32x4){0.f, 0.f, 0.f, 0.f};
    #pragma unroll
    for (int kt = 0; kt < 4; ++kt) {
        bf16x8 a[2], b[3];
        #pragma unroll
        for (int i = 0; i < 2; ++i)
            a[i] = *(const bf16x8*)(AL + ((wv * 2 + i) * 16 + m16) * 136 + kt * 32 + q * 8);
        #pragma unroll
        for (int j = 0; j < 3; ++j)
            b[j] = *(const bf16x8*)(BL + (j * 16 + m16) * 136 + kt * 32 + q * 8);
        #pragma unroll
        for (int i = 0; i < 2; ++i)
            #pragma unroll
            for (int j = 0; j < 3; ++j)
                acc[i][j] = __builtin_amdgcn_mfma_f32_16x16x32_bf16(a[i], b[j], acc[i][j], 0, 0, 0);
    }
    #pragma unroll
    for (int i = 0; i < 2; ++i) {
        #pragma unroll
        for (int r = 0; r < 4; ++r) {
            int row = rbase + (wv * 2 + i) * 16 + q * 4 + r;
            if (row < NN) {
                #pragma unroll
                for (int j = 0; j < 3; ++j)
                    Yb[(size_t)row * 64 + j * 16 + m16] = f2b(acc[i][j][r]);
            }
        }
    }
}

// ================= fused aggregate + bias + relu, F=128 =================
// wave per node; 8-deep gather MLP via lane-parallel edge metadata + shfl
__global__ __launch_bounds__(256) void k_agg128b(const int* __restrict__ offsets,
                                                 const int2* __restrict__ edges,
                                                 const float* __restrict__ dis,
                                                 const ushort* __restrict__ xw,
                                                 const float* __restrict__ bias,
                                                 ushort* __restrict__ out) {
    int wv = threadIdx.x >> 6, lane = threadIdx.x & 63;
    int n = blockIdx.x * 4 + wv;
    if (n >= NN) return;
    int beg = offsets[n], end = offsets[n + 1];
    int deg = end - beg;
    int2 em = (lane < deg) ? edges[beg + lane] : make_int2(0, 0);
    int s_l = em.x;
    float w_l = __int_as_float(em.y);
    float d = dis[n];
    uint v0 = ((const uint*)(xw + (size_t)n * 128))[lane];
    float ax = b2f(v0 & 0xffffu) * (d * d);
    float ay = b2f(v0 >> 16) * (d * d);
    int jceil = (min(deg, 64) + 7) & ~7;   // weights past deg are 0 -> no guards
    for (int j = 0; j < jceil; j += 8) {
        int s[8]; float w[8]; uint u[8];
        #pragma unroll
        for (int k = 0; k < 8; ++k) {
            s[k] = __shfl(s_l, j + k, 64);
            w[k] = __shfl(w_l, j + k, 64);
        }
        #pragma unroll
        for (int k = 0; k < 8; ++k)
            u[k] = ((const uint*)(xw + (size_t)s[k] * 128))[lane];
        #pragma unroll
        for (int k = 0; k < 8; ++k) {
            ax = fmaf(b2f(u[k] & 0xffffu), w[k], ax);
            ay = fmaf(b2f(u[k] >> 16), w[k], ay);
        }
    }
    for (int jj = beg + 64; jj < end; ++jj) {   // rare deg>64 tail
        int2 e2 = edges[jj];
        float w = __int_as_float(e2.y);
        uint u = ((const uint*)(xw + (size_t)e2.x * 128))[lane];
        ax = fmaf(b2f(u & 0xffffu), w, ax);
        ay = fmaf(b2f(u >> 16), w, ay);
    }
    float2 bv = ((const float2*)bias)[lane];
    ax = fmaxf(ax + bv.x, 0.f);
    ay = fmaxf(ay + bv.y, 0.f);
    ((uint*)(out + (size_t)n * 128))[lane] = (uint)f2b(ax) | ((uint)f2b(ay) << 16);
}

// ================= fused aggregate + bias + relu + log_softmax, F=40 =================
// xw row stride 64 (128B aligned); lanes 40..63 read zero-pad/poison, masked out
__global__ __launch_bounds__(256) void k_agg40_lsm(const int* __restrict__ offsets,
                                                   const int2* __restrict__ edges,
                                                   const float* __restrict__ dis,
                                                   const ushort* __restrict__ xw,
                                                   const float* __restrict__ bias,
                                                   float* __restrict__ out) {
    int wv = threadIdx.x >> 6, lane = threadIdx.x & 63;
    int n = blockIdx.x * 4 + wv;
    if (n >= NN) return;
    bool act = lane < 40;
    int beg = offsets[n], end = offsets[n + 1];
    int deg = end - beg;
    int2 em = (lane < deg) ? edges[beg + lane] : make_int2(0, 0);
    int s_l = em.x;
    float w_l = __int_as_float(em.y);
    float d = dis[n];
    float x = b2f(xw[(size_t)n * 64 + lane]) * (d * d);
    int jceil = (min(deg, 64) + 7) & ~7;
    for (int j = 0; j < jceil; j += 8) {
        int s[8]; float w[8]; float u[8];
        #pragma unroll
        for (int k = 0; k < 8; ++k) {
            s[k] = __shfl(s_l, j + k, 64);
            w[k] = __shfl(w_l, j + k, 64);
        }
        #pragma unroll
        for (int k = 0; k < 8; ++k)
            u[k] = b2f(xw[(size_t)s[k] * 64 + lane]);
        #pragma unroll
        for (int k = 0; k < 8; ++k) x = fmaf(u[k], w[k], x);
    }
    for (int jj = beg + 64; jj < end; ++jj) {
        int2 e2 = edges[jj];
        float w = __int_as_float(e2.y);
        x = fmaf(b2f(xw[(size_t)e2.x * 64 + lane]), w, x);
    }
    if (act) x = fmaxf(x + bias[lane], 0.f);
    float m = act ? x : -1e30f;
    #pragma unroll
    for (int o = 32; o; o >>= 1) m = fmaxf(m, __shfl_xor(m, o, 64));
    float e = act ? expf(x - m) : 0.f;
    #pragma unroll
    for (int o = 32; o; o >>= 1) e += __shfl_xor(e, o, 64);
    if (act) out[(size_t)n * 40 + lane] = x - m - logf(e);
}

// ================= launch =================
extern "C" void kernel_launch(void* const* d_in, const int* in_sizes, int n_in,
                              void* d_out, int out_size, void* d_ws, size_t ws_size,
                              hipStream_t stream) {
    const float* feat = (const float*)d_in[0];
    const int* ei = (const int*)d_in[1];
    const float* W1 = (const float*)d_in[2];
    const float* b1 = (const float*)d_in[3];
    const float* W2 = (const float*)d_in[4];
    const float* b2 = (const float*)d_in[5];
    const float* W3 = (const float*)d_in[6];
    const float* b3 = (const float*)d_in[7];
    const int* src = ei;
    const int* dst = ei + NE;
    float* out = (float*)d_out;

    char* w = (char*)d_ws;
    int* cnt = (int*)w;        w += 100352 * 4;
    float* dis = (float*)w;    w += 100352 * 4;
    int* offsets = (int*)w;    w += 100608 * 4;
    int* cursor = (int*)w;     w += 100352 * 4;
    int* blocksum = (int*)w;   w += 512 * 4;
    int* blockbase = (int*)w;  w += 512 * 4;
    int2* edges = (int2*)w;    w += 600064 * 8;
    ushort* WTall = (ushort*)w; w += 39168 * 2;
    ushort* W1T = WTall;
    ushort* W2T = WTall + 16384;
    ushort* W3T = WTall + 32768;
    ushort* bufYb = (ushort*)w; w += (size_t)NPAD * 128 * 2;
    ushort* bufXb = (ushort*)w; w += (size_t)NPAD * 128 * 2;
    ushort* Y40b = (ushort*)w;  w += (size_t)NPAD * 64 * 2;

    const int B = 256;
    #define CDIV(a, b) (((a) + (b) - 1) / (b))

    // CSR build (reused by all layers)
    k_cnt_init<<<NBLK, B, 0, stream>>>(cnt);
    k_cnt<<<CDIV(NE, B), B, 0, stream>>>(dst, cnt);
    k_blockred<<<NBLK, B, 0, stream>>>(cnt, blocksum);
    k_scanblk<<<1, B, 0, stream>>>(blocksum, blockbase);
    k_offsets<<<NBLK, B, 0, stream>>>(cnt, blockbase, offsets, cursor, dis);
    k_fill<<<CDIV(NE, B), B, 0, stream>>>(src, dst, dis, cursor, edges);
    k_castW<<<CDIV(38912, B), B, 0, stream>>>(W1, W2, W3, WTall);

    // layer 1 (fp32 input, fused cast)
    k_gemm128b<true><<<CDIV(NN, 64), B, 0, stream>>>(feat, W1T, bufYb);
    k_agg128b<<<CDIV(NN, 4), B, 0, stream>>>(offsets, edges, dis, bufYb, b1, bufXb);
    // layer 2
    k_gemm128b<false><<<CDIV(NN, 64), B, 0, stream>>>(bufXb, W2T, bufYb);
    k_agg128b<<<CDIV(NN, 4), B, 0, stream>>>(offsets, edges, dis, bufYb, b2, bufXb);
    // layer 3
    k_gemm40b<<<CDIV(NN, 128), B, 0, stream>>>(bufXb, W3T, Y40b);
    k_agg40_lsm<<<CDIV(NN, 4), B, 0, stream>>>(offsets, edges, dis, Y40b, b3, out);
    #undef CDIV
}

// Round 5
// 279.066 us; speedup vs baseline: 3.7444x; 1.0888x over previous
//
#include <hip/hip_runtime.h>
#include <hip/hip_bf16.h>

#define NN 100000   // nodes
#define NE 600000   // edges (self-loop handled analytically)
#define NBLK 391    // ceil(NN/256)
#define NPAD 100096 // row padding for 128-row GEMM tiles

typedef unsigned int uint;
typedef unsigned short ushort;
typedef __attribute__((ext_vector_type(8))) short bf16x8;
typedef __attribute__((ext_vector_type(4))) float f32x4;

__device__ __forceinline__ ushort f2b(float f) {
    union { float f; uint u; } v; v.f = f;
    return (ushort)((v.u + 0x7fffu + ((v.u >> 16) & 1u)) >> 16);
}
__device__ __forceinline__ float b2f(uint h) {
    union { uint u; float f; } v; v.u = h << 16; return v.f;
}

// ================= CSR build =================
__global__ __launch_bounds__(256) void k_cnt_init(int* __restrict__ cnt) {
    int i = blockIdx.x * 256 + threadIdx.x;
    if (i < NN) cnt[i] = 0;
}
__global__ __launch_bounds__(256) void k_cnt(const int* __restrict__ dst,
                                             int* __restrict__ cnt) {
    int e = blockIdx.x * 256 + threadIdx.x;
    if (e < NE) atomicAdd(&cnt[dst[e]], 1);
}
__global__ __launch_bounds__(256) void k_blockred(const int* __restrict__ cnt,
                                                  int* __restrict__ blocksum) {
    int t = threadIdx.x;
    int i = blockIdx.x * 256 + t;
    int c = (i < NN) ? cnt[i] : 0;
    #pragma unroll
    for (int o = 32; o; o >>= 1) c += __shfl_xor(c, o, 64);
    __shared__ int ws[4];
    if ((t & 63) == 0) ws[t >> 6] = c;
    __syncthreads();
    if (t == 0) blocksum[blockIdx.x] = ws[0] + ws[1] + ws[2] + ws[3];
}
__global__ __launch_bounds__(256) void k_scanblk(const int* __restrict__ blocksum,
                                                 int* __restrict__ blockbase) {
    __shared__ int s[NBLK];
    int t = threadIdx.x;
    for (int i = t; i < NBLK; i += 256) s[i] = blocksum[i];
    __syncthreads();
    if (t == 0) {
        int run = 0;
        for (int i = 0; i < NBLK; ++i) { int v = s[i]; s[i] = run; run += v; }
    }
    __syncthreads();
    for (int i = t; i < NBLK; i += 256) blockbase[i] = s[i];
}
// offsets + cursor + dis (fused)
__global__ __launch_bounds__(256) void k_offsets(const int* __restrict__ cnt,
                                                 const int* __restrict__ blockbase,
                                                 int* __restrict__ offsets,
                                                 int* __restrict__ cursor,
                                                 float* __restrict__ dis) {
    int t = threadIdx.x, lane = t & 63, wv = t >> 6;
    int i = blockIdx.x * 256 + t;
    int c = (i < NN) ? cnt[i] : 0;
    int x = c;
    #pragma unroll
    for (int o = 1; o < 64; o <<= 1) {
        int v = __shfl_up(x, o, 64);
        if (lane >= o) x += v;
    }
    __shared__ int wsum[4], wbase[4];
    if (lane == 63) wsum[wv] = x;
    __syncthreads();
    if (t == 0) {
        int run = 0;
        #pragma unroll
        for (int k = 0; k < 4; ++k) { wbase[k] = run; run += wsum[k]; }
    }
    __syncthreads();
    int excl = blockbase[blockIdx.x] + wbase[wv] + x - c;
    if (i < NN) {
        offsets[i] = excl;
        cursor[i] = excl;
        dis[i] = rsqrtf((float)(c + 1));
        if (i == NN - 1) offsets[NN] = excl + c;
    }
}
// bucket-fill packed edges {src, norm}
__global__ __launch_bounds__(256) void k_fill(const int* __restrict__ src,
                                              const int* __restrict__ dst,
                                              const float* __restrict__ dis,
                                              int* __restrict__ cursor,
                                              int2* __restrict__ edges) {
    int e = blockIdx.x * 256 + threadIdx.x;
    if (e < NE) {
        int s = src[e], d = dst[e];
        int pos = atomicAdd(&cursor[d], 1);
        float nr = dis[s] * dis[d];
        edges[pos] = make_int2(s, __float_as_int(nr));
    }
}

// ================= weight casts (all three in one kernel) =================
__global__ __launch_bounds__(256) void k_castW(const float* __restrict__ W1,
                                               const float* __restrict__ W2,
                                               const float* __restrict__ W3,
                                               ushort* __restrict__ WTall) {
    int o = blockIdx.x * 256 + threadIdx.x;
    if (o >= 38912) return;
    float v;
    if (o < 32768) {
        const float* W = (o < 16384) ? W1 : W2;
        int off = o & 16383;
        int n = off >> 7, k = off & 127;
        v = W[k * 128 + n];
    } else {
        int off = o - 32768;
        int n = off >> 7, k = off & 127;
        v = (n < 40) ? W3[k * 40 + n] : 0.f;
    }
    WTall[o] = f2b(v);
}

// ================= MFMA GEMM: Y[N,128] = X[N,128] @ W, K=128 =================
template <bool F32IN>
__global__ __launch_bounds__(256) void k_gemm128b(const void* __restrict__ Xin,
                                                  const ushort* __restrict__ WT,
                                                  ushort* __restrict__ Yb) {
    __shared__ ushort AL[64 * 136];
    __shared__ ushort BL[128 * 136];
    const int t = threadIdx.x;
    const int rbase = blockIdx.x * 64;
    #pragma unroll
    for (int i = 0; i < 8; ++i) {
        int ch = t + 256 * i;
        int n = ch >> 4, c = ch & 15;
        *(int4*)(BL + n * 136 + c * 8) = *(const int4*)(WT + n * 128 + c * 8);
    }
    #pragma unroll
    for (int i = 0; i < 4; ++i) {
        int ch = t + 256 * i;
        int m = ch >> 4, c = ch & 15;
        int row = min(rbase + m, NN - 1);
        if (F32IN) {
            const float* Xf = (const float*)Xin;
            float4 f0 = *(const float4*)(Xf + (size_t)row * 128 + c * 8);
            float4 f1 = *(const float4*)(Xf + (size_t)row * 128 + c * 8 + 4);
            ushort* p = AL + m * 136 + c * 8;
            p[0] = f2b(f0.x); p[1] = f2b(f0.y); p[2] = f2b(f0.z); p[3] = f2b(f0.w);
            p[4] = f2b(f1.x); p[5] = f2b(f1.y); p[6] = f2b(f1.z); p[7] = f2b(f1.w);
        } else {
            const ushort* Xb = (const ushort*)Xin;
            *(int4*)(AL + m * 136 + c * 8) =
                *(const int4*)(Xb + (size_t)row * 128 + c * 8);
        }
    }
    __syncthreads();
    const int wv = t >> 6, l = t & 63;
    const int m16 = l & 15, q = l >> 4;
    f32x4 acc[8];
    #pragma unroll
    for (int j = 0; j < 8; ++j) acc[j] = (f32x4){0.f, 0.f, 0.f, 0.f};
    #pragma unroll
    for (int kt = 0; kt < 4; ++kt) {
        bf16x8 a = *(const bf16x8*)(AL + (wv * 16 + m16) * 136 + kt * 32 + q * 8);
        #pragma unroll
        for (int j = 0; j < 8; ++j) {
            bf16x8 b = *(const bf16x8*)(BL + (j * 16 + m16) * 136 + kt * 32 + q * 8);
            acc[j] = __builtin_amdgcn_mfma_f32_16x16x32_bf16(a, b, acc[j], 0, 0, 0);
        }
    }
    #pragma unroll
    for (int r = 0; r < 4; ++r) {
        int row = rbase + wv * 16 + q * 4 + r;
        if (row < NN) {
            #pragma unroll
            for (int j = 0; j < 8; ++j)
                Yb[(size_t)row * 128 + j * 16 + m16] = f2b(acc[j][r]);
        }
    }
}

// ================= MFMA GEMM: Y[N,48pad64] = X[N,128] @ W3 =================
__global__ __launch_bounds__(256) void k_gemm40b(const ushort* __restrict__ Xb,
                                                 const ushort* __restrict__ W3T,
                                                 ushort* __restrict__ Yb) {
    __shared__ ushort AL[128 * 136];
    __shared__ ushort BL[48 * 136];
    const int t = threadIdx.x;
    const int rbase = blockIdx.x * 128;
    #pragma unroll
    for (int i = 0; i < 3; ++i) {
        int ch = t + 256 * i;
        int n = ch >> 4, c = ch & 15;
        *(int4*)(BL + n * 136 + c * 8) = *(const int4*)(W3T + n * 128 + c * 8);
    }
    #pragma unroll
    for (int i = 0; i < 8; ++i) {
        int ch = t + 256 * i;
        int m = ch >> 4, c = ch & 15;
        *(int4*)(AL + m * 136 + c * 8) =
            *(const int4*)(Xb + (size_t)(rbase + m) * 128 + c * 8);
    }
    __syncthreads();
    const int wv = t >> 6, l = t & 63;
    const int m16 = l & 15, q = l >> 4;
    f32x4 acc[2][3];
    #pragma unroll
    for (int i = 0; i < 2; ++i)
        #pragma unroll
        for (int j = 0; j < 3; ++j) acc[i][j] = (f32x4){0.f, 0.f, 0.f, 0.f};
    #pragma unroll
    for (int kt = 0; kt < 4; ++kt) {
        bf16x8 a[2], b[3];
        #pragma unroll
        for (int i = 0; i < 2; ++i)
            a[i] = *(const bf16x8*)(AL + ((wv * 2 + i) * 16 + m16) * 136 + kt * 32 + q * 8);
        #pragma unroll
        for (int j = 0; j < 3; ++j)
            b[j] = *(const bf16x8*)(BL + (j * 16 + m16) * 136 + kt * 32 + q * 8);
        #pragma unroll
        for (int i = 0; i < 2; ++i)
            #pragma unroll
            for (int j = 0; j < 3; ++j)
                acc[i][j] = __builtin_amdgcn_mfma_f32_16x16x32_bf16(a[i], b[j], acc[i][j], 0, 0, 0);
    }
    #pragma unroll
    for (int i = 0; i < 2; ++i) {
        #pragma unroll
        for (int r = 0; r < 4; ++r) {
            int row = rbase + (wv * 2 + i) * 16 + q * 4 + r;
            if (row < NN) {
                #pragma unroll
                for (int j = 0; j < 3; ++j)
                    Yb[(size_t)row * 64 + j * 16 + m16] = f2b(acc[i][j][r]);
            }
        }
    }
}

// ================= fused aggregate + bias + relu, F=128 =================
// TWO nodes per wave: half-wave (32 lanes) per node, uint2 (4 feats) per lane.
// One gather instruction serves 2 edges; one bpermute broadcasts both halves.
__global__ __launch_bounds__(256) void k_agg128b(const int* __restrict__ offsets,
                                                 const int2* __restrict__ edges,
                                                 const float* __restrict__ dis,
                                                 const ushort* __restrict__ xw,
                                                 const float* __restrict__ bias,
                                                 ushort* __restrict__ out) {
    const int t = threadIdx.x;
    const int wv = t >> 6, lane = t & 63;
    const int hl = lane & 31;              // lane within half
    const int hsel = lane & 32;            // 0 or 32
    const int n = (blockIdx.x * 4 + wv) * 2 + (lane >> 5);
    const bool nvalid = n < NN;
    const int nc = nvalid ? n : NN - 1;
    const int beg = offsets[nc], end = offsets[nc + 1];
    const int deg = end - beg;
    int2 em = (hl < deg) ? edges[beg + hl] : make_int2(0, 0);
    int s_l = em.x;
    float w_l = __int_as_float(em.y);
    float d = dis[nc];
    uint2 v0 = ((const uint2*)(xw + (size_t)nc * 128))[hl];
    float a0 = b2f(v0.x & 0xffffu) * (d * d);
    float a1 = b2f(v0.x >> 16) * (d * d);
    float a2 = b2f(v0.y & 0xffffu) * (d * d);
    float a3 = b2f(v0.y >> 16) * (d * d);
    int degc = min(deg, 32);
    int dmax = max(degc, __shfl_xor(degc, 32, 64));   // max over both halves
    int jceil = (dmax + 7) & ~7;
    for (int j = 0; j < jceil; j += 8) {
        int s[8]; float w[8]; uint2 u[8];
        #pragma unroll
        for (int k = 0; k < 8; ++k) {
            s[k] = __shfl(s_l, hsel + j + k, 64);
            w[k] = __shfl(w_l, hsel + j + k, 64);
        }
        #pragma unroll
        for (int k = 0; k < 8; ++k)
            u[k] = ((const uint2*)(xw + (size_t)s[k] * 128))[hl];
        #pragma unroll
        for (int k = 0; k < 8; ++k) {
            a0 = fmaf(b2f(u[k].x & 0xffffu), w[k], a0);
            a1 = fmaf(b2f(u[k].x >> 16), w[k], a1);
            a2 = fmaf(b2f(u[k].y & 0xffffu), w[k], a2);
            a3 = fmaf(b2f(u[k].y >> 16), w[k], a3);
        }
    }
    for (int jj = beg + 32; jj < end; ++jj) {   // deg>32 tail (rare)
        int2 e2 = edges[jj];
        float w = __int_as_float(e2.y);
        uint2 u = ((const uint2*)(xw + (size_t)e2.x * 128))[hl];
        a0 = fmaf(b2f(u.x & 0xffffu), w, a0);
        a1 = fmaf(b2f(u.x >> 16), w, a1);
        a2 = fmaf(b2f(u.y & 0xffffu), w, a2);
        a3 = fmaf(b2f(u.y >> 16), w, a3);
    }
    float4 bv = ((const float4*)bias)[hl];
    a0 = fmaxf(a0 + bv.x, 0.f);
    a1 = fmaxf(a1 + bv.y, 0.f);
    a2 = fmaxf(a2 + bv.z, 0.f);
    a3 = fmaxf(a3 + bv.w, 0.f);
    if (nvalid) {
        uint2 o;
        o.x = (uint)f2b(a0) | ((uint)f2b(a1) << 16);
        o.y = (uint)f2b(a2) | ((uint)f2b(a3) << 16);
        ((uint2*)(out + (size_t)n * 128))[hl] = o;
    }
}

// ================= fused aggregate + bias + relu + log_softmax, F=40 =================
// TWO nodes per wave; lanes 0..19 of each half hold uint (2 feats).
__global__ __launch_bounds__(256) void k_agg40_lsm(const int* __restrict__ offsets,
                                                   const int2* __restrict__ edges,
                                                   const float* __restrict__ dis,
                                                   const ushort* __restrict__ xw,
                                                   const float* __restrict__ bias,
                                                   float* __restrict__ out) {
    const int t = threadIdx.x;
    const int wv = t >> 6, lane = t & 63;
    const int hl = lane & 31;
    const int hsel = lane & 32;
    const int n = (blockIdx.x * 4 + wv) * 2 + (lane >> 5);
    const bool nvalid = n < NN;
    const int nc = nvalid ? n : NN - 1;
    const bool act = hl < 20;
    const int beg = offsets[nc], end = offsets[nc + 1];
    const int deg = end - beg;
    int2 em = (hl < deg) ? edges[beg + hl] : make_int2(0, 0);
    int s_l = em.x;
    float w_l = __int_as_float(em.y);
    float d = dis[nc];
    uint v0 = ((const uint*)(xw + (size_t)nc * 64))[hl];
    float x0 = b2f(v0 & 0xffffu) * (d * d);
    float x1 = b2f(v0 >> 16) * (d * d);
    int degc = min(deg, 32);
    int dmax = max(degc, __shfl_xor(degc, 32, 64));
    int jceil = (dmax + 7) & ~7;
    for (int j = 0; j < jceil; j += 8) {
        int s[8]; float w[8]; uint u[8];
        #pragma unroll
        for (int k = 0; k < 8; ++k) {
            s[k] = __shfl(s_l, hsel + j + k, 64);
            w[k] = __shfl(w_l, hsel + j + k, 64);
        }
        #pragma unroll
        for (int k = 0; k < 8; ++k)
            u[k] = ((const uint*)(xw + (size_t)s[k] * 64))[hl];
        #pragma unroll
        for (int k = 0; k < 8; ++k) {
            x0 = fmaf(b2f(u[k] & 0xffffu), w[k], x0);
            x1 = fmaf(b2f(u[k] >> 16), w[k], x1);
        }
    }
    for (int jj = beg + 32; jj < end; ++jj) {
        int2 e2 = edges[jj];
        float w = __int_as_float(e2.y);
        uint u = ((const uint*)(xw + (size_t)e2.x * 64))[hl];
        x0 = fmaf(b2f(u & 0xffffu), w, x0);
        x1 = fmaf(b2f(u >> 16), w, x1);
    }
    if (act) {
        float2 bv = ((const float2*)bias)[hl];
        x0 = fmaxf(x0 + bv.x, 0.f);
        x1 = fmaxf(x1 + bv.y, 0.f);
    }
    // per-half (32-lane) reductions; offsets <32 never cross halves
    float m = act ? fmaxf(x0, x1) : -1e30f;
    #pragma unroll
    for (int o = 16; o; o >>= 1) m = fmaxf(m, __shfl_xor(m, o, 64));
    float e = act ? (expf(x0 - m) + expf(x1 - m)) : 0.f;
    #pragma unroll
    for (int o = 16; o; o >>= 1) e += __shfl_xor(e, o, 64);
    if (act && nvalid) {
        float lg = m + logf(e);
        float2 o2 = make_float2(x0 - lg, x1 - lg);
        *(float2*)(out + (size_t)n * 40 + 2 * hl) = o2;
    }
}

// ================= launch =================
extern "C" void kernel_launch(void* const* d_in, const int* in_sizes, int n_in,
                              void* d_out, int out_size, void* d_ws, size_t ws_size,
                              hipStream_t stream) {
    const float* feat = (const float*)d_in[0];
    const int* ei = (const int*)d_in[1];
    const float* W1 = (const float*)d_in[2];
    const float* b1 = (const float*)d_in[3];
    const float* W2 = (const float*)d_in[4];
    const float* b2 = (const float*)d_in[5];
    const float* W3 = (const float*)d_in[6];
    const float* b3 = (const float*)d_in[7];
    const int* src = ei;
    const int* dst = ei + NE;
    float* out = (float*)d_out;

    char* w = (char*)d_ws;
    int* cnt = (int*)w;        w += 100352 * 4;
    float* dis = (float*)w;    w += 100352 * 4;
    int* offsets = (int*)w;    w += 100608 * 4;
    int* cursor = (int*)w;     w += 100352 * 4;
    int* blocksum = (int*)w;   w += 512 * 4;
    int* blockbase = (int*)w;  w += 512 * 4;
    int2* edges = (int2*)w;    w += 600064 * 8;
    ushort* WTall = (ushort*)w; w += 39168 * 2;
    ushort* W1T = WTall;
    ushort* W2T = WTall + 16384;
    ushort* W3T = WTall + 32768;
    ushort* bufYb = (ushort*)w; w += (size_t)NPAD * 128 * 2;
    ushort* bufXb = (ushort*)w; w += (size_t)NPAD * 128 * 2;
    ushort* Y40b = (ushort*)w;  w += (size_t)NPAD * 64 * 2;

    const int B = 256;
    #define CDIV(a, b) (((a) + (b) - 1) / (b))

    // CSR build (reused by all layers)
    k_cnt_init<<<NBLK, B, 0, stream>>>(cnt);
    k_cnt<<<CDIV(NE, B), B, 0, stream>>>(dst, cnt);
    k_blockred<<<NBLK, B, 0, stream>>>(cnt, blocksum);
    k_scanblk<<<1, B, 0, stream>>>(blocksum, blockbase);
    k_offsets<<<NBLK, B, 0, stream>>>(cnt, blockbase, offsets, cursor, dis);
    k_fill<<<CDIV(NE, B), B, 0, stream>>>(src, dst, dis, cursor, edges);
    k_castW<<<CDIV(38912, B), B, 0, stream>>>(W1, W2, W3, WTall);

    // layer 1 (fp32 input, fused cast)
    k_gemm128b<true><<<CDIV(NN, 64), B, 0, stream>>>(feat, W1T, bufYb);
    k_agg128b<<<CDIV(NN, 8), B, 0, stream>>>(offsets, edges, dis, bufYb, b1, bufXb);
    // layer 2
    k_gemm128b<false><<<CDIV(NN, 64), B, 0, stream>>>(bufXb, W2T, bufYb);
    k_agg128b<<<CDIV(NN, 8), B, 0, stream>>>(offsets, edges, dis, bufYb, b2, bufXb);
    // layer 3
    k_gemm40b<<<CDIV(NN, 128), B, 0, stream>>>(bufXb, W3T, Y40b);
    k_agg40_lsm<<<CDIV(NN, 8), B, 0, stream>>>(offsets, edges, dis, Y40b, b3, out);
    #undef CDIV
}

// Round 6
// 278.649 us; speedup vs baseline: 3.7500x; 1.0015x over previous
//
#include <hip/hip_runtime.h>
#include <hip/hip_bf16.h>

#define NN 100000   // nodes
#define NE 600000   // edges (self-loop handled analytically)
#define NBLK 391    // ceil(NN/256)
#define NPAD 100096 // row padding for 128-row GEMM tiles

typedef unsigned int uint;
typedef unsigned short ushort;
typedef __attribute__((ext_vector_type(8))) short bf16x8;
typedef __attribute__((ext_vector_type(4))) float f32x4;

__device__ __forceinline__ ushort f2b(float f) {
    union { float f; uint u; } v; v.f = f;
    return (ushort)((v.u + 0x7fffu + ((v.u >> 16) & 1u)) >> 16);
}
__device__ __forceinline__ uint f2b2(float lo, float hi) {
    return (uint)f2b(lo) | ((uint)f2b(hi) << 16);
}
__device__ __forceinline__ float b2f(uint h) {
    union { uint u; float f; } v; v.u = h << 16; return v.f;
}

// ================= CSR build =================
__global__ __launch_bounds__(256) void k_cnt_init(int* __restrict__ cnt) {
    int i = blockIdx.x * 256 + threadIdx.x;
    if (i < NN) cnt[i] = 0;
}
__global__ __launch_bounds__(256) void k_cnt(const int* __restrict__ dst,
                                             int* __restrict__ cnt) {
    int e = blockIdx.x * 256 + threadIdx.x;
    if (e < NE) atomicAdd(&cnt[dst[e]], 1);
}
__global__ __launch_bounds__(256) void k_blockred(const int* __restrict__ cnt,
                                                  int* __restrict__ blocksum) {
    int t = threadIdx.x;
    int i = blockIdx.x * 256 + t;
    int c = (i < NN) ? cnt[i] : 0;
    #pragma unroll
    for (int o = 32; o; o >>= 1) c += __shfl_xor(c, o, 64);
    __shared__ int ws[4];
    if ((t & 63) == 0) ws[t >> 6] = c;
    __syncthreads();
    if (t == 0) blocksum[blockIdx.x] = ws[0] + ws[1] + ws[2] + ws[3];
}
// block 0: exclusive scan of block sums; blocks 1..153: weight cast/transposes
__global__ __launch_bounds__(256) void k_scanblk_castW(const int* __restrict__ blocksum,
                                                       int* __restrict__ blockbase,
                                                       const float* __restrict__ W1,
                                                       const float* __restrict__ W2,
                                                       const float* __restrict__ W3,
                                                       ushort* __restrict__ WTall) {
    int t = threadIdx.x;
    if (blockIdx.x == 0) {
        __shared__ int s[NBLK];
        for (int i = t; i < NBLK; i += 256) s[i] = blocksum[i];
        __syncthreads();
        if (t == 0) {
            int run = 0;
            for (int i = 0; i < NBLK; ++i) { int v = s[i]; s[i] = run; run += v; }
        }
        __syncthreads();
        for (int i = t; i < NBLK; i += 256) blockbase[i] = s[i];
    } else {
        int o = (blockIdx.x - 1) * 256 + t;
        if (o >= 38912) return;
        float v;
        if (o < 32768) {
            const float* W = (o < 16384) ? W1 : W2;
            int off = o & 16383;
            int n = off >> 7, k = off & 127;
            v = W[k * 128 + n];
        } else {
            int off = o - 32768;
            int n = off >> 7, k = off & 127;
            v = (n < 40) ? W3[k * 40 + n] : 0.f;
        }
        WTall[o] = f2b(v);
    }
}
// offsets + cursor + dis (fused)
__global__ __launch_bounds__(256) void k_offsets(const int* __restrict__ cnt,
                                                 const int* __restrict__ blockbase,
                                                 int* __restrict__ offsets,
                                                 int* __restrict__ cursor,
                                                 float* __restrict__ dis) {
    int t = threadIdx.x, lane = t & 63, wv = t >> 6;
    int i = blockIdx.x * 256 + t;
    int c = (i < NN) ? cnt[i] : 0;
    int x = c;
    #pragma unroll
    for (int o = 1; o < 64; o <<= 1) {
        int v = __shfl_up(x, o, 64);
        if (lane >= o) x += v;
    }
    __shared__ int wsum[4], wbase[4];
    if (lane == 63) wsum[wv] = x;
    __syncthreads();
    if (t == 0) {
        int run = 0;
        #pragma unroll
        for (int k = 0; k < 4; ++k) { wbase[k] = run; run += wsum[k]; }
    }
    __syncthreads();
    int excl = blockbase[blockIdx.x] + wbase[wv] + x - c;
    if (i < NN) {
        offsets[i] = excl;
        cursor[i] = excl;
        dis[i] = rsqrtf((float)(c + 1));
        if (i == NN - 1) offsets[NN] = excl + c;
    }
}
// bucket-fill packed edges {src, norm}
__global__ __launch_bounds__(256) void k_fill(const int* __restrict__ src,
                                              const int* __restrict__ dst,
                                              const float* __restrict__ dis,
                                              int* __restrict__ cursor,
                                              int2* __restrict__ edges) {
    int e = blockIdx.x * 256 + threadIdx.x;
    if (e < NE) {
        int s = src[e], d = dst[e];
        int pos = atomicAdd(&cursor[d], 1);
        float nr = dis[s] * dis[d];
        edges[pos] = make_int2(s, __float_as_int(nr));
    }
}

// ================= MFMA GEMM: Y[N,128] = X[N,128] @ W, K=128 =================
template <bool F32IN>
__global__ __launch_bounds__(256) void k_gemm128b(const void* __restrict__ Xin,
                                                  const ushort* __restrict__ WT,
                                                  ushort* __restrict__ Yb) {
    __shared__ ushort AL[64 * 136];
    __shared__ ushort BL[128 * 136];
    const int t = threadIdx.x;
    const int rbase = blockIdx.x * 64;
    #pragma unroll
    for (int i = 0; i < 8; ++i) {
        int ch = t + 256 * i;
        int n = ch >> 4, c = ch & 15;
        *(int4*)(BL + n * 136 + c * 8) = *(const int4*)(WT + n * 128 + c * 8);
    }
    #pragma unroll
    for (int i = 0; i < 4; ++i) {
        int ch = t + 256 * i;
        int m = ch >> 4, c = ch & 15;
        int row = min(rbase + m, NN - 1);
        if (F32IN) {
            const float* Xf = (const float*)Xin;
            float4 f0 = *(const float4*)(Xf + (size_t)row * 128 + c * 8);
            float4 f1 = *(const float4*)(Xf + (size_t)row * 128 + c * 8 + 4);
            uint4 o;   // packed bf16 pairs -> single ds_write_b128
            o.x = f2b2(f0.x, f0.y);
            o.y = f2b2(f0.z, f0.w);
            o.z = f2b2(f1.x, f1.y);
            o.w = f2b2(f1.z, f1.w);
            *(uint4*)(AL + m * 136 + c * 8) = o;
        } else {
            const ushort* Xb = (const ushort*)Xin;
            *(int4*)(AL + m * 136 + c * 8) =
                *(const int4*)(Xb + (size_t)row * 128 + c * 8);
        }
    }
    __syncthreads();
    const int wv = t >> 6, l = t & 63;
    const int m16 = l & 15, q = l >> 4;
    f32x4 acc[8];
    #pragma unroll
    for (int j = 0; j < 8; ++j) acc[j] = (f32x4){0.f, 0.f, 0.f, 0.f};
    #pragma unroll
    for (int kt = 0; kt < 4; ++kt) {
        bf16x8 a = *(const bf16x8*)(AL + (wv * 16 + m16) * 136 + kt * 32 + q * 8);
        #pragma unroll
        for (int j = 0; j < 8; ++j) {
            bf16x8 b = *(const bf16x8*)(BL + (j * 16 + m16) * 136 + kt * 32 + q * 8);
            acc[j] = __builtin_amdgcn_mfma_f32_16x16x32_bf16(a, b, acc[j], 0, 0, 0);
        }
    }
    #pragma unroll
    for (int r = 0; r < 4; ++r) {
        int row = rbase + wv * 16 + q * 4 + r;
        if (row < NN) {
            #pragma unroll
            for (int j = 0; j < 8; ++j)
                Yb[(size_t)row * 128 + j * 16 + m16] = f2b(acc[j][r]);
        }
    }
}

// ================= MFMA GEMM: Y[N,48pad64] = X[N,128] @ W3 =================
__global__ __launch_bounds__(256) void k_gemm40b(const ushort* __restrict__ Xb,
                                                 const ushort* __restrict__ W3T,
                                                 ushort* __restrict__ Yb) {
    __shared__ ushort AL[128 * 136];
    __shared__ ushort BL[48 * 136];
    const int t = threadIdx.x;
    const int rbase = blockIdx.x * 128;
    #pragma unroll
    for (int i = 0; i < 3; ++i) {
        int ch = t + 256 * i;
        int n = ch >> 4, c = ch & 15;
        *(int4*)(BL + n * 136 + c * 8) = *(const int4*)(W3T + n * 128 + c * 8);
    }
    #pragma unroll
    for (int i = 0; i < 8; ++i) {
        int ch = t + 256 * i;
        int m = ch >> 4, c = ch & 15;
        *(int4*)(AL + m * 136 + c * 8) =
            *(const int4*)(Xb + (size_t)(rbase + m) * 128 + c * 8);
    }
    __syncthreads();
    const int wv = t >> 6, l = t & 63;
    const int m16 = l & 15, q = l >> 4;
    f32x4 acc[2][3];
    #pragma unroll
    for (int i = 0; i < 2; ++i)
        #pragma unroll
        for (int j = 0; j < 3; ++j) acc[i][j] = (f32x4){0.f, 0.f, 0.f, 0.f};
    #pragma unroll
    for (int kt = 0; kt < 4; ++kt) {
        bf16x8 a[2], b[3];
        #pragma unroll
        for (int i = 0; i < 2; ++i)
            a[i] = *(const bf16x8*)(AL + ((wv * 2 + i) * 16 + m16) * 136 + kt * 32 + q * 8);
        #pragma unroll
        for (int j = 0; j < 3; ++j)
            b[j] = *(const bf16x8*)(BL + (j * 16 + m16) * 136 + kt * 32 + q * 8);
        #pragma unroll
        for (int i = 0; i < 2; ++i)
            #pragma unroll
            for (int j = 0; j < 3; ++j)
                acc[i][j] = __builtin_amdgcn_mfma_f32_16x16x32_bf16(a[i], b[j], acc[i][j], 0, 0, 0);
    }
    #pragma unroll
    for (int i = 0; i < 2; ++i) {
        #pragma unroll
        for (int r = 0; r < 4; ++r) {
            int row = rbase + (wv * 2 + i) * 16 + q * 4 + r;
            if (row < NN) {
                #pragma unroll
                for (int j = 0; j < 3; ++j)
                    Yb[(size_t)row * 64 + j * 16 + m16] = f2b(acc[i][j][r]);
            }
        }
    }
}

// ================= fused aggregate + bias + relu, F=128 =================
// FOUR nodes per wave: quarter-wave (16 lanes) per node, uint4 (8 feats)/lane.
// One gather instruction serves 4 edges; one shuffle pair serves 4 edges.
__global__ __launch_bounds__(256) void k_agg128b(const int* __restrict__ offsets,
                                                 const int2* __restrict__ edges,
                                                 const float* __restrict__ dis,
                                                 const ushort* __restrict__ xw,
                                                 const float* __restrict__ bias,
                                                 ushort* __restrict__ out) {
    const int t = threadIdx.x;
    const int wv = t >> 6, lane = t & 63;
    const int hl = lane & 15;              // lane within quarter
    const int qsel = lane & 48;            // 0,16,32,48
    const int n = (blockIdx.x * 4 + wv) * 4 + (lane >> 4);
    const bool nvalid = n < NN;
    const int nc = nvalid ? n : NN - 1;
    const int beg = offsets[nc], end = offsets[nc + 1];
    const int deg = end - beg;
    int2 em = (hl < deg) ? edges[beg + hl] : make_int2(0, 0);
    int s_l = em.x;
    float w_l = __int_as_float(em.y);
    float d = dis[nc];
    float dd = d * d;
    uint4 v0 = ((const uint4*)(xw + (size_t)nc * 128))[hl];
    float a0 = b2f(v0.x & 0xffffu) * dd, a1 = b2f(v0.x >> 16) * dd;
    float a2 = b2f(v0.y & 0xffffu) * dd, a3 = b2f(v0.y >> 16) * dd;
    float a4 = b2f(v0.z & 0xffffu) * dd, a5 = b2f(v0.z >> 16) * dd;
    float a6 = b2f(v0.w & 0xffffu) * dd, a7 = b2f(v0.w >> 16) * dd;
    int degc = min(deg, 16);
    int m1 = max(degc, __shfl_xor(degc, 16, 64));
    int dmax = max(m1, __shfl_xor(m1, 32, 64));   // max over 4 quarters
    int jceil = (dmax + 7) & ~7;
    for (int j = 0; j < jceil; j += 8) {
        int s[8]; float w[8]; uint4 u[8];
        #pragma unroll
        for (int k = 0; k < 8; ++k) {
            s[k] = __shfl(s_l, qsel + j + k, 64);
            w[k] = __shfl(w_l, qsel + j + k, 64);
        }
        #pragma unroll
        for (int k = 0; k < 8; ++k)
            u[k] = ((const uint4*)(xw + (size_t)s[k] * 128))[hl];
        #pragma unroll
        for (int k = 0; k < 8; ++k) {
            a0 = fmaf(b2f(u[k].x & 0xffffu), w[k], a0);
            a1 = fmaf(b2f(u[k].x >> 16), w[k], a1);
            a2 = fmaf(b2f(u[k].y & 0xffffu), w[k], a2);
            a3 = fmaf(b2f(u[k].y >> 16), w[k], a3);
            a4 = fmaf(b2f(u[k].z & 0xffffu), w[k], a4);
            a5 = fmaf(b2f(u[k].z >> 16), w[k], a5);
            a6 = fmaf(b2f(u[k].w & 0xffffu), w[k], a6);
            a7 = fmaf(b2f(u[k].w >> 16), w[k], a7);
        }
    }
    for (int jj = beg + 16; jj < end; ++jj) {   // deg>16 tail (rare)
        int2 e2 = edges[jj];
        float w = __int_as_float(e2.y);
        uint4 u = ((const uint4*)(xw + (size_t)e2.x * 128))[hl];
        a0 = fmaf(b2f(u.x & 0xffffu), w, a0);
        a1 = fmaf(b2f(u.x >> 16), w, a1);
        a2 = fmaf(b2f(u.y & 0xffffu), w, a2);
        a3 = fmaf(b2f(u.y >> 16), w, a3);
        a4 = fmaf(b2f(u.z & 0xffffu), w, a4);
        a5 = fmaf(b2f(u.z >> 16), w, a5);
        a6 = fmaf(b2f(u.w & 0xffffu), w, a6);
        a7 = fmaf(b2f(u.w >> 16), w, a7);
    }
    float4 bv0 = ((const float4*)bias)[2 * hl];
    float4 bv1 = ((const float4*)bias)[2 * hl + 1];
    a0 = fmaxf(a0 + bv0.x, 0.f); a1 = fmaxf(a1 + bv0.y, 0.f);
    a2 = fmaxf(a2 + bv0.z, 0.f); a3 = fmaxf(a3 + bv0.w, 0.f);
    a4 = fmaxf(a4 + bv1.x, 0.f); a5 = fmaxf(a5 + bv1.y, 0.f);
    a6 = fmaxf(a6 + bv1.z, 0.f); a7 = fmaxf(a7 + bv1.w, 0.f);
    if (nvalid) {
        uint4 o;
        o.x = f2b2(a0, a1);
        o.y = f2b2(a2, a3);
        o.z = f2b2(a4, a5);
        o.w = f2b2(a6, a7);
        ((uint4*)(out + (size_t)n * 128))[hl] = o;
    }
}

// ================= fused aggregate + bias + relu + log_softmax, F=40 =================
// TWO nodes per wave; lanes 0..19 of each half hold uint (2 feats).
__global__ __launch_bounds__(256) void k_agg40_lsm(const int* __restrict__ offsets,
                                                   const int2* __restrict__ edges,
                                                   const float* __restrict__ dis,
                                                   const ushort* __restrict__ xw,
                                                   const float* __restrict__ bias,
                                                   float* __restrict__ out) {
    const int t = threadIdx.x;
    const int wv = t >> 6, lane = t & 63;
    const int hl = lane & 31;
    const int hsel = lane & 32;
    const int n = (blockIdx.x * 4 + wv) * 2 + (lane >> 5);
    const bool nvalid = n < NN;
    const int nc = nvalid ? n : NN - 1;
    const bool act = hl < 20;
    const int beg = offsets[nc], end = offsets[nc + 1];
    const int deg = end - beg;
    int2 em = (hl < deg) ? edges[beg + hl] : make_int2(0, 0);
    int s_l = em.x;
    float w_l = __int_as_float(em.y);
    float d = dis[nc];
    uint v0 = ((const uint*)(xw + (size_t)nc * 64))[hl];
    float x0 = b2f(v0 & 0xffffu) * (d * d);
    float x1 = b2f(v0 >> 16) * (d * d);
    int degc = min(deg, 32);
    int dmax = max(degc, __shfl_xor(degc, 32, 64));
    int jceil = (dmax + 7) & ~7;
    for (int j = 0; j < jceil; j += 8) {
        int s[8]; float w[8]; uint u[8];
        #pragma unroll
        for (int k = 0; k < 8; ++k) {
            s[k] = __shfl(s_l, hsel + j + k, 64);
            w[k] = __shfl(w_l, hsel + j + k, 64);
        }
        #pragma unroll
        for (int k = 0; k < 8; ++k)
            u[k] = ((const uint*)(xw + (size_t)s[k] * 64))[hl];
        #pragma unroll
        for (int k = 0; k < 8; ++k) {
            x0 = fmaf(b2f(u[k] & 0xffffu), w[k], x0);
            x1 = fmaf(b2f(u[k] >> 16), w[k], x1);
        }
    }
    for (int jj = beg + 32; jj < end; ++jj) {
        int2 e2 = edges[jj];
        float w = __int_as_float(e2.y);
        uint u = ((const uint*)(xw + (size_t)e2.x * 64))[hl];
        x0 = fmaf(b2f(u & 0xffffu), w, x0);
        x1 = fmaf(b2f(u >> 16), w, x1);
    }
    if (act) {
        float2 bv = ((const float2*)bias)[hl];
        x0 = fmaxf(x0 + bv.x, 0.f);
        x1 = fmaxf(x1 + bv.y, 0.f);
    }
    float m = act ? fmaxf(x0, x1) : -1e30f;
    #pragma unroll
    for (int o = 16; o; o >>= 1) m = fmaxf(m, __shfl_xor(m, o, 64));
    float e = act ? (expf(x0 - m) + expf(x1 - m)) : 0.f;
    #pragma unroll
    for (int o = 16; o; o >>= 1) e += __shfl_xor(e, o, 64);
    if (act && nvalid) {
        float lg = m + logf(e);
        float2 o2 = make_float2(x0 - lg, x1 - lg);
        *(float2*)(out + (size_t)n * 40 + 2 * hl) = o2;
    }
}

// ================= launch =================
extern "C" void kernel_launch(void* const* d_in, const int* in_sizes, int n_in,
                              void* d_out, int out_size, void* d_ws, size_t ws_size,
                              hipStream_t stream) {
    const float* feat = (const float*)d_in[0];
    const int* ei = (const int*)d_in[1];
    const float* W1 = (const float*)d_in[2];
    const float* b1 = (const float*)d_in[3];
    const float* W2 = (const float*)d_in[4];
    const float* b2 = (const float*)d_in[5];
    const float* W3 = (const float*)d_in[6];
    const float* b3 = (const float*)d_in[7];
    const int* src = ei;
    const int* dst = ei + NE;
    float* out = (float*)d_out;

    char* w = (char*)d_ws;
    int* cnt = (int*)w;        w += 100352 * 4;
    float* dis = (float*)w;    w += 100352 * 4;
    int* offsets = (int*)w;    w += 100608 * 4;
    int* cursor = (int*)w;     w += 100352 * 4;
    int* blocksum = (int*)w;   w += 512 * 4;
    int* blockbase = (int*)w;  w += 512 * 4;
    int2* edges = (int2*)w;    w += 600064 * 8;
    ushort* WTall = (ushort*)w; w += 39168 * 2;
    ushort* W1T = WTall;
    ushort* W2T = WTall + 16384;
    ushort* W3T = WTall + 32768;
    ushort* bufYb = (ushort*)w; w += (size_t)NPAD * 128 * 2;
    ushort* bufXb = (ushort*)w; w += (size_t)NPAD * 128 * 2;
    ushort* Y40b = (ushort*)w;  w += (size_t)NPAD * 64 * 2;

    const int B = 256;
    #define CDIV(a, b) (((a) + (b) - 1) / (b))

    // CSR build (reused by all layers); weight cast piggybacks on the scan launch
    k_cnt_init<<<NBLK, B, 0, stream>>>(cnt);
    k_cnt<<<CDIV(NE, B), B, 0, stream>>>(dst, cnt);
    k_blockred<<<NBLK, B, 0, stream>>>(cnt, blocksum);
    k_scanblk_castW<<<1 + CDIV(38912, B), B, 0, stream>>>(blocksum, blockbase,
                                                          W1, W2, W3, WTall);
    k_offsets<<<NBLK, B, 0, stream>>>(cnt, blockbase, offsets, cursor, dis);
    k_fill<<<CDIV(NE, B), B, 0, stream>>>(src, dst, dis, cursor, edges);

    // layer 1 (fp32 input, fused cast)
    k_gemm128b<true><<<CDIV(NN, 64), B, 0, stream>>>(feat, W1T, bufYb);
    k_agg128b<<<CDIV(NN, 16), B, 0, stream>>>(offsets, edges, dis, bufYb, b1, bufXb);
    // layer 2
    k_gemm128b<false><<<CDIV(NN, 64), B, 0, stream>>>(bufXb, W2T, bufYb);
    k_agg128b<<<CDIV(NN, 16), B, 0, stream>>>(offsets, edges, dis, bufYb, b2, bufXb);
    // layer 3
    k_gemm40b<<<CDIV(NN, 128), B, 0, stream>>>(bufXb, W3T, Y40b);
    k_agg40_lsm<<<CDIV(NN, 8), B, 0, stream>>>(offsets, edges, dis, Y40b, b3, out);
    #undef CDIV
}

// Round 7
// 259.497 us; speedup vs baseline: 4.0268x; 1.0738x over previous
//
#include <hip/hip_runtime.h>
#include <hip/hip_bf16.h>

#define NN 100000   // nodes
#define NE 600000   // edges (self-loop handled analytically)
#define NBLK 391    // ceil(NN/256)
#define NPAD 100096 // row padding for 128-row GEMM tiles (row NN = zero row)

typedef unsigned int uint;
typedef unsigned short ushort;
typedef __attribute__((ext_vector_type(8))) short bf16x8;
typedef __attribute__((ext_vector_type(4))) float f32x4;

__device__ __forceinline__ ushort f2b(float f) {
    union { float f; uint u; } v; v.f = f;
    return (ushort)((v.u + 0x7fffu + ((v.u >> 16) & 1u)) >> 16);
}
__device__ __forceinline__ uint f2b2(float lo, float hi) {
    return (uint)f2b(lo) | ((uint)f2b(hi) << 16);
}
__device__ __forceinline__ float b2f(uint h) {
    union { uint u; float f; } v; v.u = h << 16; return v.f;
}

// ================= CSR build =================
__global__ __launch_bounds__(256) void k_cnt_init(int* __restrict__ cnt) {
    int i = blockIdx.x * 256 + threadIdx.x;
    if (i < NN) cnt[i] = 0;
}
// count + save per-edge rank within its dst bucket (coalesced store)
__global__ __launch_bounds__(256) void k_cnt(const int* __restrict__ dst,
                                             int* __restrict__ cnt,
                                             int* __restrict__ rank) {
    int e = blockIdx.x * 256 + threadIdx.x;
    if (e < NE) rank[e] = atomicAdd(&cnt[dst[e]], 1);
}
__global__ __launch_bounds__(256) void k_blockred(const int* __restrict__ cnt,
                                                  int* __restrict__ blocksum) {
    int t = threadIdx.x;
    int i = blockIdx.x * 256 + t;
    int c = (i < NN) ? cnt[i] : 0;
    #pragma unroll
    for (int o = 32; o; o >>= 1) c += __shfl_xor(c, o, 64);
    __shared__ int ws[4];
    if ((t & 63) == 0) ws[t >> 6] = c;
    __syncthreads();
    if (t == 0) blocksum[blockIdx.x] = ws[0] + ws[1] + ws[2] + ws[3];
}
// block 0: exclusive scan of block sums; blocks 1..152: weight cast/transposes
__global__ __launch_bounds__(256) void k_scanblk_castW(const int* __restrict__ blocksum,
                                                       int* __restrict__ blockbase,
                                                       const float* __restrict__ W1,
                                                       const float* __restrict__ W2,
                                                       const float* __restrict__ W3,
                                                       ushort* __restrict__ WTall) {
    int t = threadIdx.x;
    if (blockIdx.x == 0) {
        __shared__ int s[NBLK];
        for (int i = t; i < NBLK; i += 256) s[i] = blocksum[i];
        __syncthreads();
        if (t == 0) {
            int run = 0;
            for (int i = 0; i < NBLK; ++i) { int v = s[i]; s[i] = run; run += v; }
        }
        __syncthreads();
        for (int i = t; i < NBLK; i += 256) blockbase[i] = s[i];
    } else {
        int o = (blockIdx.x - 1) * 256 + t;
        if (o >= 38912) return;
        float v;
        if (o < 32768) {
            const float* W = (o < 16384) ? W1 : W2;
            int off = o & 16383;
            int n = off >> 7, k = off & 127;
            v = W[k * 128 + n];
        } else {
            int off = o - 32768;
            int n = off >> 7, k = off & 127;
            v = (n < 40) ? W3[k * 40 + n] : 0.f;
        }
        WTall[o] = f2b(v);
    }
}
// offsets + dis (fused)
__global__ __launch_bounds__(256) void k_offsets(const int* __restrict__ cnt,
                                                 const int* __restrict__ blockbase,
                                                 int* __restrict__ offsets,
                                                 float* __restrict__ dis) {
    int t = threadIdx.x, lane = t & 63, wv = t >> 6;
    int i = blockIdx.x * 256 + t;
    int c = (i < NN) ? cnt[i] : 0;
    int x = c;
    #pragma unroll
    for (int o = 1; o < 64; o <<= 1) {
        int v = __shfl_up(x, o, 64);
        if (lane >= o) x += v;
    }
    __shared__ int wsum[4], wbase[4];
    if (lane == 63) wsum[wv] = x;
    __syncthreads();
    if (t == 0) {
        int run = 0;
        #pragma unroll
        for (int k = 0; k < 4; ++k) { wbase[k] = run; run += wsum[k]; }
    }
    __syncthreads();
    int excl = blockbase[blockIdx.x] + wbase[wv] + x - c;
    if (i < NN) {
        offsets[i] = excl;
        dis[i] = rsqrtf((float)(c + 1));
        if (i == NN - 1) offsets[NN] = excl + c;
    }
}
// bucket-fill src indices, atomic-free (position = offsets[dst] + rank)
__global__ __launch_bounds__(256) void k_fill(const int* __restrict__ src,
                                              const int* __restrict__ dst,
                                              const int* __restrict__ rank,
                                              const int* __restrict__ offsets,
                                              int* __restrict__ edges) {
    int e = blockIdx.x * 256 + threadIdx.x;
    if (e < NE) {
        int s = src[e], d = dst[e], r = rank[e];
        edges[offsets[d] + r] = s;
    }
}

// ================= MFMA GEMM: G[N,128] = dis[row] * (X[N,128] @ W) =================
template <bool F32IN>
__global__ __launch_bounds__(256) void k_gemm128b(const void* __restrict__ Xin,
                                                  const ushort* __restrict__ WT,
                                                  const float* __restrict__ dis,
                                                  ushort* __restrict__ Yb) {
    __shared__ ushort AL[64 * 136];
    __shared__ ushort BL[128 * 136];
    const int t = threadIdx.x;
    const int rbase = blockIdx.x * 64;
    // zero row NN (gather target for inactive edge lanes in agg)
    if (blockIdx.x == 0 && t < 16) {
        uint4 z = make_uint4(0, 0, 0, 0);
        ((uint4*)(Yb + (size_t)NN * 128))[t] = z;
    }
    #pragma unroll
    for (int i = 0; i < 8; ++i) {
        int ch = t + 256 * i;
        int n = ch >> 4, c = ch & 15;
        *(int4*)(BL + n * 136 + c * 8) = *(const int4*)(WT + n * 128 + c * 8);
    }
    #pragma unroll
    for (int i = 0; i < 4; ++i) {
        int ch = t + 256 * i;
        int m = ch >> 4, c = ch & 15;
        int row = min(rbase + m, NN - 1);
        if (F32IN) {
            const float* Xf = (const float*)Xin;
            float4 f0 = *(const float4*)(Xf + (size_t)row * 128 + c * 8);
            float4 f1 = *(const float4*)(Xf + (size_t)row * 128 + c * 8 + 4);
            uint4 o;
            o.x = f2b2(f0.x, f0.y);
            o.y = f2b2(f0.z, f0.w);
            o.z = f2b2(f1.x, f1.y);
            o.w = f2b2(f1.z, f1.w);
            *(uint4*)(AL + m * 136 + c * 8) = o;
        } else {
            const ushort* Xb = (const ushort*)Xin;
            *(int4*)(AL + m * 136 + c * 8) =
                *(const int4*)(Xb + (size_t)row * 128 + c * 8);
        }
    }
    __syncthreads();
    const int wv = t >> 6, l = t & 63;
    const int m16 = l & 15, q = l >> 4;
    f32x4 acc[8];
    #pragma unroll
    for (int j = 0; j < 8; ++j) acc[j] = (f32x4){0.f, 0.f, 0.f, 0.f};
    #pragma unroll
    for (int kt = 0; kt < 4; ++kt) {
        bf16x8 a = *(const bf16x8*)(AL + (wv * 16 + m16) * 136 + kt * 32 + q * 8);
        #pragma unroll
        for (int j = 0; j < 8; ++j) {
            bf16x8 b = *(const bf16x8*)(BL + (j * 16 + m16) * 136 + kt * 32 + q * 8);
            acc[j] = __builtin_amdgcn_mfma_f32_16x16x32_bf16(a, b, acc[j], 0, 0, 0);
        }
    }
    #pragma unroll
    for (int r = 0; r < 4; ++r) {
        int row = rbase + wv * 16 + q * 4 + r;
        if (row < NN) {
            float ds = dis[row];
            #pragma unroll
            for (int j = 0; j < 8; ++j)
                Yb[(size_t)row * 128 + j * 16 + m16] = f2b(acc[j][r] * ds);
        }
    }
}

// ================= MFMA GEMM: G[N,48pad64] = dis[row] * (X @ W3) =================
__global__ __launch_bounds__(256) void k_gemm40b(const ushort* __restrict__ Xb,
                                                 const ushort* __restrict__ W3T,
                                                 const float* __restrict__ dis,
                                                 ushort* __restrict__ Yb) {
    __shared__ ushort AL[128 * 136];
    __shared__ ushort BL[48 * 136];
    const int t = threadIdx.x;
    const int rbase = blockIdx.x * 128;
    if (blockIdx.x == 0 && t < 8) {
        uint4 z = make_uint4(0, 0, 0, 0);
        ((uint4*)(Yb + (size_t)NN * 64))[t] = z;
    }
    #pragma unroll
    for (int i = 0; i < 3; ++i) {
        int ch = t + 256 * i;
        int n = ch >> 4, c = ch & 15;
        *(int4*)(BL + n * 136 + c * 8) = *(const int4*)(W3T + n * 128 + c * 8);
    }
    #pragma unroll
    for (int i = 0; i < 8; ++i) {
        int ch = t + 256 * i;
        int m = ch >> 4, c = ch & 15;
        int row = min(rbase + m, NN - 1);
        *(int4*)(AL + m * 136 + c * 8) =
            *(const int4*)(Xb + (size_t)row * 128 + c * 8);
    }
    __syncthreads();
    const int wv = t >> 6, l = t & 63;
    const int m16 = l & 15, q = l >> 4;
    f32x4 acc[2][3];
    #pragma unroll
    for (int i = 0; i < 2; ++i)
        #pragma unroll
        for (int j = 0; j < 3; ++j) acc[i][j] = (f32x4){0.f, 0.f, 0.f, 0.f};
    #pragma unroll
    for (int kt = 0; kt < 4; ++kt) {
        bf16x8 a[2], b[3];
        #pragma unroll
        for (int i = 0; i < 2; ++i)
            a[i] = *(const bf16x8*)(AL + ((wv * 2 + i) * 16 + m16) * 136 + kt * 32 + q * 8);
        #pragma unroll
        for (int j = 0; j < 3; ++j)
            b[j] = *(const bf16x8*)(BL + (j * 16 + m16) * 136 + kt * 32 + q * 8);
        #pragma unroll
        for (int i = 0; i < 2; ++i)
            #pragma unroll
            for (int j = 0; j < 3; ++j)
                acc[i][j] = __builtin_amdgcn_mfma_f32_16x16x32_bf16(a[i], b[j], acc[i][j], 0, 0, 0);
    }
    #pragma unroll
    for (int i = 0; i < 2; ++i) {
        #pragma unroll
        for (int r = 0; r < 4; ++r) {
            int row = rbase + (wv * 2 + i) * 16 + q * 4 + r;
            if (row < NN) {
                float ds = dis[row];
                #pragma unroll
                for (int j = 0; j < 3; ++j)
                    Yb[(size_t)row * 64 + j * 16 + m16] = f2b(acc[i][j][r] * ds);
            }
        }
    }
}

// ================= fused aggregate + bias + relu, F=128 =================
// 4 nodes/wave, unweighted row sum; out = relu(dis[n]*acc + b).
// Inactive edge lanes gather the zeroed row NN.
__global__ __launch_bounds__(256) void k_agg128b(const int* __restrict__ offsets,
                                                 const int* __restrict__ edges,
                                                 const float* __restrict__ dis,
                                                 const ushort* __restrict__ xw,
                                                 const float* __restrict__ bias,
                                                 ushort* __restrict__ out) {
    const int t = threadIdx.x;
    const int wv = t >> 6, lane = t & 63;
    const int hl = lane & 15;
    const int qsel = lane & 48;
    const int n = (blockIdx.x * 4 + wv) * 4 + (lane >> 4);
    const bool nvalid = n < NN;
    const int nc = nvalid ? n : NN - 1;
    const int beg = offsets[nc], end = offsets[nc + 1];
    const int deg = end - beg;
    int s_l = (hl < deg) ? edges[beg + hl] : NN;   // NN = zero row
    uint4 v0 = ((const uint4*)(xw + (size_t)nc * 128))[hl];
    float a0 = b2f(v0.x & 0xffffu), a1 = b2f(v0.x >> 16);
    float a2 = b2f(v0.y & 0xffffu), a3 = b2f(v0.y >> 16);
    float a4 = b2f(v0.z & 0xffffu), a5 = b2f(v0.z >> 16);
    float a6 = b2f(v0.w & 0xffffu), a7 = b2f(v0.w >> 16);
    int degc = min(deg, 16);
    int m1 = max(degc, __shfl_xor(degc, 16, 64));
    int dmax = max(m1, __shfl_xor(m1, 32, 64));
    int jceil = (dmax + 7) & ~7;
    for (int j = 0; j < jceil; j += 8) {
        int s[8]; uint4 u[8];
        #pragma unroll
        for (int k = 0; k < 8; ++k) s[k] = __shfl(s_l, qsel + j + k, 64);
        #pragma unroll
        for (int k = 0; k < 8; ++k)
            u[k] = ((const uint4*)(xw + (size_t)s[k] * 128))[hl];
        #pragma unroll
        for (int k = 0; k < 8; ++k) {
            a0 += b2f(u[k].x & 0xffffu); a1 += b2f(u[k].x >> 16);
            a2 += b2f(u[k].y & 0xffffu); a3 += b2f(u[k].y >> 16);
            a4 += b2f(u[k].z & 0xffffu); a5 += b2f(u[k].z >> 16);
            a6 += b2f(u[k].w & 0xffffu); a7 += b2f(u[k].w >> 16);
        }
    }
    for (int jj = beg + 16; jj < end; ++jj) {   // deg>16 tail (rare)
        int s2 = edges[jj];
        uint4 u = ((const uint4*)(xw + (size_t)s2 * 128))[hl];
        a0 += b2f(u.x & 0xffffu); a1 += b2f(u.x >> 16);
        a2 += b2f(u.y & 0xffffu); a3 += b2f(u.y >> 16);
        a4 += b2f(u.z & 0xffffu); a5 += b2f(u.z >> 16);
        a6 += b2f(u.w & 0xffffu); a7 += b2f(u.w >> 16);
    }
    float d = dis[nc];
    float4 bv0 = ((const float4*)bias)[2 * hl];
    float4 bv1 = ((const float4*)bias)[2 * hl + 1];
    a0 = fmaxf(fmaf(a0, d, bv0.x), 0.f); a1 = fmaxf(fmaf(a1, d, bv0.y), 0.f);
    a2 = fmaxf(fmaf(a2, d, bv0.z), 0.f); a3 = fmaxf(fmaf(a3, d, bv0.w), 0.f);
    a4 = fmaxf(fmaf(a4, d, bv1.x), 0.f); a5 = fmaxf(fmaf(a5, d, bv1.y), 0.f);
    a6 = fmaxf(fmaf(a6, d, bv1.z), 0.f); a7 = fmaxf(fmaf(a7, d, bv1.w), 0.f);
    if (nvalid) {
        uint4 o;
        o.x = f2b2(a0, a1);
        o.y = f2b2(a2, a3);
        o.z = f2b2(a4, a5);
        o.w = f2b2(a6, a7);
        ((uint4*)(out + (size_t)n * 128))[hl] = o;
    }
}

// ================= fused aggregate + bias + relu + log_softmax, F=40 =================
__global__ __launch_bounds__(256) void k_agg40_lsm(const int* __restrict__ offsets,
                                                   const int* __restrict__ edges,
                                                   const float* __restrict__ dis,
                                                   const ushort* __restrict__ xw,
                                                   const float* __restrict__ bias,
                                                   float* __restrict__ out) {
    const int t = threadIdx.x;
    const int wv = t >> 6, lane = t & 63;
    const int hl = lane & 31;
    const int hsel = lane & 32;
    const int n = (blockIdx.x * 4 + wv) * 2 + (lane >> 5);
    const bool nvalid = n < NN;
    const int nc = nvalid ? n : NN - 1;
    const bool act = hl < 20;
    const int beg = offsets[nc], end = offsets[nc + 1];
    const int deg = end - beg;
    int s_l = (hl < deg) ? edges[beg + hl] : NN;
    uint v0 = ((const uint*)(xw + (size_t)nc * 64))[hl];
    float x0 = b2f(v0 & 0xffffu);
    float x1 = b2f(v0 >> 16);
    int degc = min(deg, 32);
    int dmax = max(degc, __shfl_xor(degc, 32, 64));
    int jceil = (dmax + 7) & ~7;
    for (int j = 0; j < jceil; j += 8) {
        int s[8]; uint u[8];
        #pragma unroll
        for (int k = 0; k < 8; ++k) s[k] = __shfl(s_l, hsel + j + k, 64);
        #pragma unroll
        for (int k = 0; k < 8; ++k)
            u[k] = ((const uint*)(xw + (size_t)s[k] * 64))[hl];
        #pragma unroll
        for (int k = 0; k < 8; ++k) {
            x0 += b2f(u[k] & 0xffffu);
            x1 += b2f(u[k] >> 16);
        }
    }
    for (int jj = beg + 32; jj < end; ++jj) {
        int s2 = edges[jj];
        uint u = ((const uint*)(xw + (size_t)s2 * 64))[hl];
        x0 += b2f(u & 0xffffu);
        x1 += b2f(u >> 16);
    }
    float d = dis[nc];
    if (act) {
        float2 bv = ((const float2*)bias)[hl];
        x0 = fmaxf(fmaf(x0, d, bv.x), 0.f);
        x1 = fmaxf(fmaf(x1, d, bv.y), 0.f);
    }
    float m = act ? fmaxf(x0, x1) : -1e30f;
    #pragma unroll
    for (int o = 16; o; o >>= 1) m = fmaxf(m, __shfl_xor(m, o, 64));
    float e = act ? (expf(x0 - m) + expf(x1 - m)) : 0.f;
    #pragma unroll
    for (int o = 16; o; o >>= 1) e += __shfl_xor(e, o, 64);
    if (act && nvalid) {
        float lg = m + logf(e);
        float2 o2 = make_float2(x0 - lg, x1 - lg);
        *(float2*)(out + (size_t)n * 40 + 2 * hl) = o2;
    }
}

// ================= launch =================
extern "C" void kernel_launch(void* const* d_in, const int* in_sizes, int n_in,
                              void* d_out, int out_size, void* d_ws, size_t ws_size,
                              hipStream_t stream) {
    const float* feat = (const float*)d_in[0];
    const int* ei = (const int*)d_in[1];
    const float* W1 = (const float*)d_in[2];
    const float* b1 = (const float*)d_in[3];
    const float* W2 = (const float*)d_in[4];
    const float* b2 = (const float*)d_in[5];
    const float* W3 = (const float*)d_in[6];
    const float* b3 = (const float*)d_in[7];
    const int* src = ei;
    const int* dst = ei + NE;
    float* out = (float*)d_out;

    char* w = (char*)d_ws;
    int* cnt = (int*)w;        w += 100352 * 4;
    float* dis = (float*)w;    w += 100352 * 4;
    int* offsets = (int*)w;    w += 100608 * 4;
    int* rank = (int*)w;       w += 600064 * 4;
    int* blocksum = (int*)w;   w += 512 * 4;
    int* blockbase = (int*)w;  w += 512 * 4;
    int* edges = (int*)w;      w += 600064 * 4;
    ushort* WTall = (ushort*)w; w += 39168 * 2;
    ushort* W1T = WTall;
    ushort* W2T = WTall + 16384;
    ushort* W3T = WTall + 32768;
    ushort* bufYb = (ushort*)w; w += (size_t)NPAD * 128 * 2;
    ushort* bufXb = (ushort*)w; w += (size_t)NPAD * 128 * 2;
    ushort* Y40b = (ushort*)w;  w += (size_t)NPAD * 64 * 2;

    const int B = 256;
    #define CDIV(a, b) (((a) + (b) - 1) / (b))

    // CSR build (reused by all layers); weight cast piggybacks on the scan launch
    k_cnt_init<<<NBLK, B, 0, stream>>>(cnt);
    k_cnt<<<CDIV(NE, B), B, 0, stream>>>(dst, cnt, rank);
    k_blockred<<<NBLK, B, 0, stream>>>(cnt, blocksum);
    k_scanblk_castW<<<1 + CDIV(38912, B), B, 0, stream>>>(blocksum, blockbase,
                                                          W1, W2, W3, WTall);
    k_offsets<<<NBLK, B, 0, stream>>>(cnt, blockbase, offsets, dis);
    k_fill<<<CDIV(NE, B), B, 0, stream>>>(src, dst, rank, offsets, edges);

    // layer 1 (fp32 input, fused cast; epilogue scales by dis)
    k_gemm128b<true><<<CDIV(NN, 64), B, 0, stream>>>(feat, W1T, dis, bufYb);
    k_agg128b<<<CDIV(NN, 16), B, 0, stream>>>(offsets, edges, dis, bufYb, b1, bufXb);
    // layer 2
    k_gemm128b<false><<<CDIV(NN, 64), B, 0, stream>>>(bufXb, W2T, dis, bufYb);
    k_agg128b<<<CDIV(NN, 16), B, 0, stream>>>(offsets, edges, dis, bufYb, b2, bufXb);
    // layer 3
    k_gemm40b<<<CDIV(NN, 128), B, 0, stream>>>(bufXb, W3T, dis, Y40b);
    k_agg40_lsm<<<CDIV(NN, 8), B, 0, stream>>>(offsets, edges, dis, Y40b, b3, out);
    #undef CDIV
}

// Round 8
// 248.690 us; speedup vs baseline: 4.2018x; 1.0435x over previous
//
#include <hip/hip_runtime.h>
#include <hip/hip_bf16.h>

#define NN 100000   // nodes
#define NE 600000   // edges (self-loop handled analytically)
#define NBLK 391    // ceil(NN/256)
#define NPAD 100096 // row padding for GEMM tiles (row NN = zero row)

typedef unsigned int uint;
typedef unsigned short ushort;
typedef __attribute__((ext_vector_type(8))) short bf16x8;
typedef __attribute__((ext_vector_type(4))) float f32x4;

__device__ __forceinline__ ushort f2b(float f) {
    union { float f; uint u; } v; v.f = f;
    return (ushort)((v.u + 0x7fffu + ((v.u >> 16) & 1u)) >> 16);
}
__device__ __forceinline__ uint f2b2(float lo, float hi) {
    return (uint)f2b(lo) | ((uint)f2b(hi) << 16);
}
__device__ __forceinline__ float b2f(uint h) {
    union { uint u; float f; } v; v.u = h << 16; return v.f;
}

// ================= CSR build =================
// blocks [0,NBLK): init cnt; blocks [NBLK, ...): cast/transpose weights
__global__ __launch_bounds__(256) void k_init_castW(int* __restrict__ cnt,
                                                    const float* __restrict__ W1,
                                                    const float* __restrict__ W2,
                                                    const float* __restrict__ W3,
                                                    ushort* __restrict__ WTall) {
    int t = threadIdx.x;
    if (blockIdx.x < NBLK) {
        int i = blockIdx.x * 256 + t;
        if (i < NN) cnt[i] = 0;
    } else {
        int o = (blockIdx.x - NBLK) * 256 + t;
        if (o >= 38912) return;
        float v;
        if (o < 32768) {
            const float* W = (o < 16384) ? W1 : W2;
            int off = o & 16383;
            int n = off >> 7, k = off & 127;
            v = W[k * 128 + n];
        } else {
            int off = o - 32768;
            int n = off >> 7, k = off & 127;
            v = (n < 40) ? W3[k * 40 + n] : 0.f;
        }
        WTall[o] = f2b(v);
    }
}
// count + save per-edge rank within its dst bucket (coalesced store)
__global__ __launch_bounds__(256) void k_cnt(const int* __restrict__ dst,
                                             int* __restrict__ cnt,
                                             int* __restrict__ rank) {
    int e = blockIdx.x * 256 + threadIdx.x;
    if (e < NE) rank[e] = atomicAdd(&cnt[dst[e]], 1);
}
__global__ __launch_bounds__(256) void k_blockred(const int* __restrict__ cnt,
                                                  int* __restrict__ blocksum) {
    int t = threadIdx.x;
    int i = blockIdx.x * 256 + t;
    int c = (i < NN) ? cnt[i] : 0;
    #pragma unroll
    for (int o = 32; o; o >>= 1) c += __shfl_xor(c, o, 64);
    __shared__ int ws[4];
    if ((t & 63) == 0) ws[t >> 6] = c;
    __syncthreads();
    if (t == 0) blocksum[blockIdx.x] = ws[0] + ws[1] + ws[2] + ws[3];
}
__global__ __launch_bounds__(256) void k_scanblk(const int* __restrict__ blocksum,
                                                 int* __restrict__ blockbase) {
    __shared__ int s[NBLK];
    int t = threadIdx.x;
    for (int i = t; i < NBLK; i += 256) s[i] = blocksum[i];
    __syncthreads();
    if (t == 0) {
        int run = 0;
        for (int i = 0; i < NBLK; ++i) { int v = s[i]; s[i] = run; run += v; }
    }
    __syncthreads();
    for (int i = t; i < NBLK; i += 256) blockbase[i] = s[i];
}
// offsets + dis (fused)
__global__ __launch_bounds__(256) void k_offsets(const int* __restrict__ cnt,
                                                 const int* __restrict__ blockbase,
                                                 int* __restrict__ offsets,
                                                 float* __restrict__ dis) {
    int t = threadIdx.x, lane = t & 63, wv = t >> 6;
    int i = blockIdx.x * 256 + t;
    int c = (i < NN) ? cnt[i] : 0;
    int x = c;
    #pragma unroll
    for (int o = 1; o < 64; o <<= 1) {
        int v = __shfl_up(x, o, 64);
        if (lane >= o) x += v;
    }
    __shared__ int wsum[4], wbase[4];
    if (lane == 63) wsum[wv] = x;
    __syncthreads();
    if (t == 0) {
        int run = 0;
        #pragma unroll
        for (int k = 0; k < 4; ++k) { wbase[k] = run; run += wsum[k]; }
    }
    __syncthreads();
    int excl = blockbase[blockIdx.x] + wbase[wv] + x - c;
    if (i < NN) {
        offsets[i] = excl;
        dis[i] = rsqrtf((float)(c + 1));
        if (i == NN - 1) offsets[NN] = excl + c;
    }
}
// bucket-fill src indices, atomic-free (position = offsets[dst] + rank)
__global__ __launch_bounds__(256) void k_fill(const int* __restrict__ src,
                                              const int* __restrict__ dst,
                                              const int* __restrict__ rank,
                                              const int* __restrict__ offsets,
                                              int* __restrict__ edges) {
    int e = blockIdx.x * 256 + threadIdx.x;
    if (e < NE) {
        int s = src[e], d = dst[e], r = rank[e];
        edges[offsets[d] + r] = s;
    }
}

// ================= GEMM layer 1: G1[N,128] = dis[row]*(feat @ W1), fp32 in =========
__global__ __launch_bounds__(256) void k_gemm1(const float* __restrict__ Xf,
                                               const ushort* __restrict__ WT,
                                               const float* __restrict__ dis,
                                               ushort* __restrict__ Yb) {
    __shared__ ushort AL[64 * 136];
    __shared__ ushort BL[128 * 136];
    const int t = threadIdx.x;
    const int rbase = blockIdx.x * 64;
    if (blockIdx.x == 0 && t < 16) {   // zero row NN (gather target for pad lanes)
        uint4 z = make_uint4(0, 0, 0, 0);
        ((uint4*)(Yb + (size_t)NN * 128))[t] = z;
    }
    #pragma unroll
    for (int i = 0; i < 8; ++i) {
        int ch = t + 256 * i;
        int n = ch >> 4, c = ch & 15;
        *(int4*)(BL + n * 136 + c * 8) = *(const int4*)(WT + n * 128 + c * 8);
    }
    #pragma unroll
    for (int i = 0; i < 4; ++i) {
        int ch = t + 256 * i;
        int m = ch >> 4, c = ch & 15;
        int row = min(rbase + m, NN - 1);
        float4 f0 = *(const float4*)(Xf + (size_t)row * 128 + c * 8);
        float4 f1 = *(const float4*)(Xf + (size_t)row * 128 + c * 8 + 4);
        uint4 o;
        o.x = f2b2(f0.x, f0.y);
        o.y = f2b2(f0.z, f0.w);
        o.z = f2b2(f1.x, f1.y);
        o.w = f2b2(f1.z, f1.w);
        *(uint4*)(AL + m * 136 + c * 8) = o;
    }
    __syncthreads();
    const int wv = t >> 6, l = t & 63;
    const int m16 = l & 15, q = l >> 4;
    f32x4 acc[8];
    #pragma unroll
    for (int j = 0; j < 8; ++j) acc[j] = (f32x4){0.f, 0.f, 0.f, 0.f};
    #pragma unroll
    for (int kt = 0; kt < 4; ++kt) {
        bf16x8 a = *(const bf16x8*)(AL + (wv * 16 + m16) * 136 + kt * 32 + q * 8);
        #pragma unroll
        for (int j = 0; j < 8; ++j) {
            bf16x8 b = *(const bf16x8*)(BL + (j * 16 + m16) * 136 + kt * 32 + q * 8);
            acc[j] = __builtin_amdgcn_mfma_f32_16x16x32_bf16(a, b, acc[j], 0, 0, 0);
        }
    }
    #pragma unroll
    for (int r = 0; r < 4; ++r) {
        int row = rbase + wv * 16 + q * 4 + r;
        if (row < NN) {
            float ds = dis[row];
            #pragma unroll
            for (int j = 0; j < 8; ++j)
                Yb[(size_t)row * 128 + j * 16 + m16] = f2b(acc[j][r] * ds);
        }
    }
}

// ======= FUSED: aggregate(G_prev) + bias + relu -> LDS -> GEMM(W,128) -> G_next =======
// Block owns 64 rows. Agg: 16 quarters (4 waves x 4) x 4 sequential nodes each;
// quarter lane hl holds feats [8hl,8hl+8). Result packed straight into MFMA A-tile.
__global__ __launch_bounds__(256) void k_fused128(const int* __restrict__ offsets,
                                                  const int* __restrict__ edges,
                                                  const float* __restrict__ dis,
                                                  const ushort* __restrict__ xw,
                                                  const float* __restrict__ bias,
                                                  const ushort* __restrict__ WT,
                                                  ushort* __restrict__ out) {
    __shared__ ushort AL[64 * 136];
    __shared__ ushort BL[128 * 136];
    const int t = threadIdx.x;
    const int rbase = blockIdx.x * 64;
    if (blockIdx.x == 0 && t < 16) {   // zero row NN of the OUTPUT buffer
        uint4 z = make_uint4(0, 0, 0, 0);
        ((uint4*)(out + (size_t)NN * 128))[t] = z;
    }
    // stage B (independent of agg; overlaps its latency)
    #pragma unroll
    for (int i = 0; i < 8; ++i) {
        int ch = t + 256 * i;
        int n = ch >> 4, c = ch & 15;
        *(int4*)(BL + n * 136 + c * 8) = *(const int4*)(WT + n * 128 + c * 8);
    }
    const int wv = t >> 6, lane = t & 63;
    const int hl = lane & 15;
    const int qsel = lane & 48;
    const int qid = wv * 4 + (lane >> 4);   // 0..15
    #pragma unroll
    for (int iter = 0; iter < 4; ++iter) {
        const int m = qid * 4 + iter;
        const int n = rbase + m;
        const int nc = min(n, NN - 1);
        const int beg = offsets[nc], end = offsets[nc + 1];
        const int deg = end - beg;
        int s_l = (hl < deg) ? edges[beg + hl] : NN;   // NN = zero row
        uint4 v0 = ((const uint4*)(xw + (size_t)nc * 128))[hl];
        float a0 = b2f(v0.x & 0xffffu), a1 = b2f(v0.x >> 16);
        float a2 = b2f(v0.y & 0xffffu), a3 = b2f(v0.y >> 16);
        float a4 = b2f(v0.z & 0xffffu), a5 = b2f(v0.z >> 16);
        float a6 = b2f(v0.w & 0xffffu), a7 = b2f(v0.w >> 16);
        int degc = min(deg, 16);
        int m1 = max(degc, __shfl_xor(degc, 16, 64));
        int dmax = max(m1, __shfl_xor(m1, 32, 64));
        int jceil = (dmax + 7) & ~7;
        for (int j = 0; j < jceil; j += 8) {
            int s[8]; uint4 u[8];
            #pragma unroll
            for (int k = 0; k < 8; ++k) s[k] = __shfl(s_l, qsel + j + k, 64);
            #pragma unroll
            for (int k = 0; k < 8; ++k)
                u[k] = ((const uint4*)(xw + (size_t)s[k] * 128))[hl];
            #pragma unroll
            for (int k = 0; k < 8; ++k) {
                a0 += b2f(u[k].x & 0xffffu); a1 += b2f(u[k].x >> 16);
                a2 += b2f(u[k].y & 0xffffu); a3 += b2f(u[k].y >> 16);
                a4 += b2f(u[k].z & 0xffffu); a5 += b2f(u[k].z >> 16);
                a6 += b2f(u[k].w & 0xffffu); a7 += b2f(u[k].w >> 16);
            }
        }
        for (int jj = beg + 16; jj < end; ++jj) {   // deg>16 tail (rare)
            int s2 = edges[jj];
            uint4 u = ((const uint4*)(xw + (size_t)s2 * 128))[hl];
            a0 += b2f(u.x & 0xffffu); a1 += b2f(u.x >> 16);
            a2 += b2f(u.y & 0xffffu); a3 += b2f(u.y >> 16);
            a4 += b2f(u.z & 0xffffu); a5 += b2f(u.z >> 16);
            a6 += b2f(u.w & 0xffffu); a7 += b2f(u.w >> 16);
        }
        float d = dis[nc];
        float4 bv0 = ((const float4*)bias)[2 * hl];
        float4 bv1 = ((const float4*)bias)[2 * hl + 1];
        a0 = fmaxf(fmaf(a0, d, bv0.x), 0.f); a1 = fmaxf(fmaf(a1, d, bv0.y), 0.f);
        a2 = fmaxf(fmaf(a2, d, bv0.z), 0.f); a3 = fmaxf(fmaf(a3, d, bv0.w), 0.f);
        a4 = fmaxf(fmaf(a4, d, bv1.x), 0.f); a5 = fmaxf(fmaf(a5, d, bv1.y), 0.f);
        a6 = fmaxf(fmaf(a6, d, bv1.z), 0.f); a7 = fmaxf(fmaf(a7, d, bv1.w), 0.f);
        uint4 o;
        o.x = f2b2(a0, a1);
        o.y = f2b2(a2, a3);
        o.z = f2b2(a4, a5);
        o.w = f2b2(a6, a7);
        *(uint4*)(AL + m * 136 + hl * 8) = o;
    }
    __syncthreads();
    // GEMM phase (identical to k_gemm1 compute)
    const int m16 = lane & 15, q = lane >> 4;
    f32x4 acc[8];
    #pragma unroll
    for (int j = 0; j < 8; ++j) acc[j] = (f32x4){0.f, 0.f, 0.f, 0.f};
    #pragma unroll
    for (int kt = 0; kt < 4; ++kt) {
        bf16x8 a = *(const bf16x8*)(AL + (wv * 16 + m16) * 136 + kt * 32 + q * 8);
        #pragma unroll
        for (int j = 0; j < 8; ++j) {
            bf16x8 b = *(const bf16x8*)(BL + (j * 16 + m16) * 136 + kt * 32 + q * 8);
            acc[j] = __builtin_amdgcn_mfma_f32_16x16x32_bf16(a, b, acc[j], 0, 0, 0);
        }
    }
    #pragma unroll
    for (int r = 0; r < 4; ++r) {
        int row = rbase + wv * 16 + q * 4 + r;
        if (row < NN) {
            float ds = dis[row];
            #pragma unroll
            for (int j = 0; j < 8; ++j)
                out[(size_t)row * 128 + j * 16 + m16] = f2b(acc[j][r] * ds);
        }
    }
}

// ======= FUSED: aggregate(G2) + bias + relu -> LDS -> GEMM(W3,48) -> Y40b =======
__global__ __launch_bounds__(256) void k_fused40(const int* __restrict__ offsets,
                                                 const int* __restrict__ edges,
                                                 const float* __restrict__ dis,
                                                 const ushort* __restrict__ xw,
                                                 const float* __restrict__ bias,
                                                 const ushort* __restrict__ W3T,
                                                 ushort* __restrict__ out) {
    __shared__ ushort AL[64 * 136];
    __shared__ ushort BL[48 * 136];
    const int t = threadIdx.x;
    const int rbase = blockIdx.x * 64;
    if (blockIdx.x == 0 && t < 8) {   // zero row NN of Y40b (stride 64)
        uint4 z = make_uint4(0, 0, 0, 0);
        ((uint4*)(out + (size_t)NN * 64))[t] = z;
    }
    #pragma unroll
    for (int i = 0; i < 3; ++i) {
        int ch = t + 256 * i;
        int n = ch >> 4, c = ch & 15;
        *(int4*)(BL + n * 136 + c * 8) = *(const int4*)(W3T + n * 128 + c * 8);
    }
    const int wv = t >> 6, lane = t & 63;
    const int hl = lane & 15;
    const int qsel = lane & 48;
    const int qid = wv * 4 + (lane >> 4);
    #pragma unroll
    for (int iter = 0; iter < 4; ++iter) {
        const int m = qid * 4 + iter;
        const int n = rbase + m;
        const int nc = min(n, NN - 1);
        const int beg = offsets[nc], end = offsets[nc + 1];
        const int deg = end - beg;
        int s_l = (hl < deg) ? edges[beg + hl] : NN;
        uint4 v0 = ((const uint4*)(xw + (size_t)nc * 128))[hl];
        float a0 = b2f(v0.x & 0xffffu), a1 = b2f(v0.x >> 16);
        float a2 = b2f(v0.y & 0xffffu), a3 = b2f(v0.y >> 16);
        float a4 = b2f(v0.z & 0xffffu), a5 = b2f(v0.z >> 16);
        float a6 = b2f(v0.w & 0xffffu), a7 = b2f(v0.w >> 16);
        int degc = min(deg, 16);
        int m1 = max(degc, __shfl_xor(degc, 16, 64));
        int dmax = max(m1, __shfl_xor(m1, 32, 64));
        int jceil = (dmax + 7) & ~7;
        for (int j = 0; j < jceil; j += 8) {
            int s[8]; uint4 u[8];
            #pragma unroll
            for (int k = 0; k < 8; ++k) s[k] = __shfl(s_l, qsel + j + k, 64);
            #pragma unroll
            for (int k = 0; k < 8; ++k)
                u[k] = ((const uint4*)(xw + (size_t)s[k] * 128))[hl];
            #pragma unroll
            for (int k = 0; k < 8; ++k) {
                a0 += b2f(u[k].x & 0xffffu); a1 += b2f(u[k].x >> 16);
                a2 += b2f(u[k].y & 0xffffu); a3 += b2f(u[k].y >> 16);
                a4 += b2f(u[k].z & 0xffffu); a5 += b2f(u[k].z >> 16);
                a6 += b2f(u[k].w & 0xffffu); a7 += b2f(u[k].w >> 16);
            }
        }
        for (int jj = beg + 16; jj < end; ++jj) {
            int s2 = edges[jj];
            uint4 u = ((const uint4*)(xw + (size_t)s2 * 128))[hl];
            a0 += b2f(u.x & 0xffffu); a1 += b2f(u.x >> 16);
            a2 += b2f(u.y & 0xffffu); a3 += b2f(u.y >> 16);
            a4 += b2f(u.z & 0xffffu); a5 += b2f(u.z >> 16);
            a6 += b2f(u.w & 0xffffu); a7 += b2f(u.w >> 16);
        }
        float d = dis[nc];
        float4 bv0 = ((const float4*)bias)[2 * hl];
        float4 bv1 = ((const float4*)bias)[2 * hl + 1];
        a0 = fmaxf(fmaf(a0, d, bv0.x), 0.f); a1 = fmaxf(fmaf(a1, d, bv0.y), 0.f);
        a2 = fmaxf(fmaf(a2, d, bv0.z), 0.f); a3 = fmaxf(fmaf(a3, d, bv0.w), 0.f);
        a4 = fmaxf(fmaf(a4, d, bv1.x), 0.f); a5 = fmaxf(fmaf(a5, d, bv1.y), 0.f);
        a6 = fmaxf(fmaf(a6, d, bv1.z), 0.f); a7 = fmaxf(fmaf(a7, d, bv1.w), 0.f);
        uint4 o;
        o.x = f2b2(a0, a1);
        o.y = f2b2(a2, a3);
        o.z = f2b2(a4, a5);
        o.w = f2b2(a6, a7);
        *(uint4*)(AL + m * 136 + hl * 8) = o;
    }
    __syncthreads();
    // GEMM phase: each wave = 16 rows x 48 cols (3 n-tiles)
    const int m16 = lane & 15, q = lane >> 4;
    f32x4 acc[3];
    #pragma unroll
    for (int j = 0; j < 3; ++j) acc[j] = (f32x4){0.f, 0.f, 0.f, 0.f};
    #pragma unroll
    for (int kt = 0; kt < 4; ++kt) {
        bf16x8 a = *(const bf16x8*)(AL + (wv * 16 + m16) * 136 + kt * 32 + q * 8);
        #pragma unroll
        for (int j = 0; j < 3; ++j) {
            bf16x8 b = *(const bf16x8*)(BL + (j * 16 + m16) * 136 + kt * 32 + q * 8);
            acc[j] = __builtin_amdgcn_mfma_f32_16x16x32_bf16(a, b, acc[j], 0, 0, 0);
        }
    }
    #pragma unroll
    for (int r = 0; r < 4; ++r) {
        int row = rbase + wv * 16 + q * 4 + r;
        if (row < NN) {
            float ds = dis[row];
            #pragma unroll
            for (int j = 0; j < 3; ++j)
                out[(size_t)row * 64 + j * 16 + m16] = f2b(acc[j][r] * ds);
        }
    }
}

// ================= fused aggregate + bias + relu + log_softmax, F=40 =================
__global__ __launch_bounds__(256) void k_agg40_lsm(const int* __restrict__ offsets,
                                                   const int* __restrict__ edges,
                                                   const float* __restrict__ dis,
                                                   const ushort* __restrict__ xw,
                                                   const float* __restrict__ bias,
                                                   float* __restrict__ out) {
    const int t = threadIdx.x;
    const int wv = t >> 6, lane = t & 63;
    const int hl = lane & 31;
    const int hsel = lane & 32;
    const int n = (blockIdx.x * 4 + wv) * 2 + (lane >> 5);
    const bool nvalid = n < NN;
    const int nc = nvalid ? n : NN - 1;
    const bool act = hl < 20;
    const int beg = offsets[nc], end = offsets[nc + 1];
    const int deg = end - beg;
    int s_l = (hl < deg) ? edges[beg + hl] : NN;
    uint v0 = ((const uint*)(xw + (size_t)nc * 64))[hl];
    float x0 = b2f(v0 & 0xffffu);
    float x1 = b2f(v0 >> 16);
    int degc = min(deg, 32);
    int dmax = max(degc, __shfl_xor(degc, 32, 64));
    int jceil = (dmax + 7) & ~7;
    for (int j = 0; j < jceil; j += 8) {
        int s[8]; uint u[8];
        #pragma unroll
        for (int k = 0; k < 8; ++k) s[k] = __shfl(s_l, hsel + j + k, 64);
        #pragma unroll
        for (int k = 0; k < 8; ++k)
            u[k] = ((const uint*)(xw + (size_t)s[k] * 64))[hl];
        #pragma unroll
        for (int k = 0; k < 8; ++k) {
            x0 += b2f(u[k] & 0xffffu);
            x1 += b2f(u[k] >> 16);
        }
    }
    for (int jj = beg + 32; jj < end; ++jj) {
        int s2 = edges[jj];
        uint u = ((const uint*)(xw + (size_t)s2 * 64))[hl];
        x0 += b2f(u & 0xffffu);
        x1 += b2f(u >> 16);
    }
    float d = dis[nc];
    if (act) {
        float2 bv = ((const float2*)bias)[hl];
        x0 = fmaxf(fmaf(x0, d, bv.x), 0.f);
        x1 = fmaxf(fmaf(x1, d, bv.y), 0.f);
    }
    float m = act ? fmaxf(x0, x1) : -1e30f;
    #pragma unroll
    for (int o = 16; o; o >>= 1) m = fmaxf(m, __shfl_xor(m, o, 64));
    float e = act ? (expf(x0 - m) + expf(x1 - m)) : 0.f;
    #pragma unroll
    for (int o = 16; o; o >>= 1) e += __shfl_xor(e, o, 64);
    if (act && nvalid) {
        float lg = m + logf(e);
        float2 o2 = make_float2(x0 - lg, x1 - lg);
        *(float2*)(out + (size_t)n * 40 + 2 * hl) = o2;
    }
}

// ================= launch =================
extern "C" void kernel_launch(void* const* d_in, const int* in_sizes, int n_in,
                              void* d_out, int out_size, void* d_ws, size_t ws_size,
                              hipStream_t stream) {
    const float* feat = (const float*)d_in[0];
    const int* ei = (const int*)d_in[1];
    const float* W1 = (const float*)d_in[2];
    const float* b1 = (const float*)d_in[3];
    const float* W2 = (const float*)d_in[4];
    const float* b2 = (const float*)d_in[5];
    const float* W3 = (const float*)d_in[6];
    const float* b3 = (const float*)d_in[7];
    const int* src = ei;
    const int* dst = ei + NE;
    float* out = (float*)d_out;

    char* w = (char*)d_ws;
    int* cnt = (int*)w;        w += 100352 * 4;
    float* dis = (float*)w;    w += 100352 * 4;
    int* offsets = (int*)w;    w += 100608 * 4;
    int* rank = (int*)w;       w += 600064 * 4;
    int* blocksum = (int*)w;   w += 512 * 4;
    int* blockbase = (int*)w;  w += 512 * 4;
    int* edges = (int*)w;      w += 600064 * 4;
    ushort* WTall = (ushort*)w; w += 39168 * 2;
    ushort* W1T = WTall;
    ushort* W2T = WTall + 16384;
    ushort* W3T = WTall + 32768;
    ushort* bufYb = (ushort*)w; w += (size_t)NPAD * 128 * 2;
    ushort* bufXb = (ushort*)w; w += (size_t)NPAD * 128 * 2;
    ushort* Y40b = (ushort*)w;  w += (size_t)NPAD * 64 * 2;

    const int B = 256;
    #define CDIV(a, b) (((a) + (b) - 1) / (b))

    // CSR build (reused by all layers); weight cast rides the first launch
    k_init_castW<<<NBLK + CDIV(38912, B), B, 0, stream>>>(cnt, W1, W2, W3, WTall);
    k_cnt<<<CDIV(NE, B), B, 0, stream>>>(dst, cnt, rank);
    k_blockred<<<NBLK, B, 0, stream>>>(cnt, blocksum);
    k_scanblk<<<1, B, 0, stream>>>(blocksum, blockbase);
    k_offsets<<<NBLK, B, 0, stream>>>(cnt, blockbase, offsets, dis);
    k_fill<<<CDIV(NE, B), B, 0, stream>>>(src, dst, rank, offsets, edges);

    // layer 1 GEMM (fp32 input, fused cast; epilogue scales by dis)
    k_gemm1<<<CDIV(NN, 64), B, 0, stream>>>(feat, W1T, dis, bufYb);
    // fused agg1 + gemm2
    k_fused128<<<CDIV(NN, 64), B, 0, stream>>>(offsets, edges, dis, bufYb, b1, W2T, bufXb);
    // fused agg2 + gemm40
    k_fused40<<<CDIV(NN, 64), B, 0, stream>>>(offsets, edges, dis, bufXb, b2, W3T, Y40b);
    // final aggregate + log_softmax
    k_agg40_lsm<<<CDIV(NN, 8), B, 0, stream>>>(offsets, edges, dis, Y40b, b3, out);
    #undef CDIV
}